// Round 1
// baseline (738.370 us; speedup 1.0000x reference)
//
#include <hip/hip_runtime.h>
#include <math.h>

#define NQ 256      // D
#define CF 128      // channels (IN == OUT)
#define NHD 32      // head dim
#define RS 0.17677669529663687f  // 1/sqrt(32)

// ---------------------------------------------------------------------------
// K1: projection GEMM: Out[row,o] = sum_ic ef[row,ic] * W[ic,o]
// grid (2048, 3) block 256. 32 rows x 128 cols per block, 4x4 microtile.
// W staged in LDS in two 64-ic halves (32KB), input tile transposed (8KB).
// ---------------------------------------------------------------------------
extern "C" __global__ __launch_bounds__(256) void k_proj(
    const float* __restrict__ ef, const float* __restrict__ Wq,
    const float* __restrict__ Wk, const float* __restrict__ Wv,
    float* __restrict__ Qb, float* __restrict__ Kb, float* __restrict__ Vb)
{
  __shared__ float Wl[64 * 128];   // 32KB: one ic-half of W
  __shared__ float inT[64][32];    // 8KB: [ic_local][row] transposed input tile
  const float* W = (blockIdx.y == 0) ? Wq : (blockIdx.y == 1) ? Wk : Wv;
  float* Out = (blockIdx.y == 0) ? Qb : (blockIdx.y == 1) ? Kb : Vb;
  const int t = threadIdx.x;
  const int row0 = blockIdx.x * 32;
  const int cg = t & 31, rg = t >> 5;
  const int o0 = cg * 4, r0 = rg * 4;
  float acc[4][4] = {};
  for (int hc = 0; hc < 2; ++hc) {
    __syncthreads();
    for (int i = t * 4; i < 64 * 128; i += 1024)
      *(float4*)&Wl[i] = *(const float4*)&W[hc * 64 * 128 + i];
    {
      const int le = t >> 3, icb = (t & 7) * 8;
      const float* src = &ef[(size_t)(row0 + le) * CF + hc * 64 + icb];
      float4 v0 = *(const float4*)src;
      float4 v1 = *(const float4*)(src + 4);
      inT[icb + 0][le] = v0.x; inT[icb + 1][le] = v0.y;
      inT[icb + 2][le] = v0.z; inT[icb + 3][le] = v0.w;
      inT[icb + 4][le] = v1.x; inT[icb + 5][le] = v1.y;
      inT[icb + 6][le] = v1.z; inT[icb + 7][le] = v1.w;
    }
    __syncthreads();
    #pragma unroll 8
    for (int ic = 0; ic < 64; ++ic) {
      float4 a = *(const float4*)&inT[ic][r0];
      float4 b = *(const float4*)&Wl[ic * 128 + o0];
      float av[4] = {a.x, a.y, a.z, a.w};
      float bv[4] = {b.x, b.y, b.z, b.w};
      #pragma unroll
      for (int i = 0; i < 4; ++i)
        #pragma unroll
        for (int j = 0; j < 4; ++j)
          acc[i][j] = fmaf(av[i], bv[j], acc[i][j]);
    }
  }
  #pragma unroll
  for (int i = 0; i < 4; ++i)
    *(float4*)&Out[(size_t)(row0 + r0 + i) * CF + o0] =
        make_float4(acc[i][0], acc[i][1], acc[i][2], acc[i][3]);
}

// ---------------------------------------------------------------------------
// K2: fused attention for one (slice, head).
// mode 0 (col attn, slice = column c): scores[q,k] = Q[q,c,h]·K[k,c,h], mask
//   where off_diag_mask[k,c]==0; out[q,c,h,:]  = 0.5 * softmax·V   (store)
// mode 1 (row attn, slice = row r):    scores[q,k] = Q[r,q,h]·K[r,k,h], mask
//   where off_diag_mask[r,k]==0; out[r,q,h,:] += 0.5 * softmax·V   (accum)
// grid (256, 4) block 128; each thread owns q = t and q = t+128.
// K,V slice staged f32 in LDS (64KB). Per-thread online softmax.
// ---------------------------------------------------------------------------
extern "C" __global__ __launch_bounds__(128) void k_attn(
    const float* __restrict__ Qg, const float* __restrict__ Kg,
    const float* __restrict__ Vg, const float* __restrict__ maskg,
    float* __restrict__ outb, const int mode)
{
  __shared__ float Kl[256][32];
  __shared__ float Vl[256][32];
  const int cr = blockIdx.x;
  const int h = blockIdx.y;
  const int t = threadIdx.x;
  for (int k = t >> 3; k < 256; k += 16) {
    const int d0 = (t & 7) * 4;
    size_t base = (mode == 0) ? ((size_t)(k * NQ + cr) * CF + h * NHD)
                              : ((size_t)(cr * NQ + k) * CF + h * NHD);
    *(float4*)&Kl[k][d0] = *(const float4*)&Kg[base + d0];
    *(float4*)&Vl[k][d0] = *(const float4*)&Vg[base + d0];
  }
  const float* maskp = (mode == 0) ? (maskg + cr) : (maskg + (size_t)cr * NQ);
  const int mstride = (mode == 0) ? NQ : 1;
  const int qa = t, qb = t + 128;
  const size_t baseA = (mode == 0) ? ((size_t)(qa * NQ + cr) * CF + h * NHD)
                                   : ((size_t)(cr * NQ + qa) * CF + h * NHD);
  const size_t baseB = (mode == 0) ? ((size_t)(qb * NQ + cr) * CF + h * NHD)
                                   : ((size_t)(cr * NQ + qb) * CF + h * NHD);
  float q0[32], q1[32];
  #pragma unroll
  for (int d4 = 0; d4 < 8; ++d4) {
    float4 v = *(const float4*)&Qg[baseA + d4 * 4];
    q0[d4*4+0] = v.x; q0[d4*4+1] = v.y; q0[d4*4+2] = v.z; q0[d4*4+3] = v.w;
    float4 w = *(const float4*)&Qg[baseB + d4 * 4];
    q1[d4*4+0] = w.x; q1[d4*4+1] = w.y; q1[d4*4+2] = w.z; q1[d4*4+3] = w.w;
  }
  __syncthreads();
  float m0 = -INFINITY, m1 = -INFINITY, l0 = 0.f, l1 = 0.f;
  float acc0[32], acc1[32];
  #pragma unroll
  for (int d = 0; d < 32; ++d) { acc0[d] = 0.f; acc1[d] = 0.f; }
  for (int k = 0; k < 256; ++k) {
    const float mv = maskp[k * mstride];
    if (mv == 0.f) continue;   // where(mask==0, -inf): excluded from softmax
    float s0 = 0.f, s1 = 0.f;
    #pragma unroll
    for (int d4 = 0; d4 < 8; ++d4) {
      float4 kv = *(const float4*)&Kl[k][d4 * 4];
      s0 = fmaf(q0[d4*4+0], kv.x, s0); s0 = fmaf(q0[d4*4+1], kv.y, s0);
      s0 = fmaf(q0[d4*4+2], kv.z, s0); s0 = fmaf(q0[d4*4+3], kv.w, s0);
      s1 = fmaf(q1[d4*4+0], kv.x, s1); s1 = fmaf(q1[d4*4+1], kv.y, s1);
      s1 = fmaf(q1[d4*4+2], kv.z, s1); s1 = fmaf(q1[d4*4+3], kv.w, s1);
    }
    s0 *= RS; s1 *= RS;
    if (s0 > m0) {
      const float f = __expf(m0 - s0);
      m0 = s0; l0 *= f;
      #pragma unroll
      for (int d = 0; d < 32; ++d) acc0[d] *= f;
    }
    if (s1 > m1) {
      const float f = __expf(m1 - s1);
      m1 = s1; l1 *= f;
      #pragma unroll
      for (int d = 0; d < 32; ++d) acc1[d] *= f;
    }
    const float p0 = __expf(s0 - m0);
    const float p1 = __expf(s1 - m1);
    l0 += p0; l1 += p1;
    #pragma unroll
    for (int d4 = 0; d4 < 8; ++d4) {
      float4 vv = *(const float4*)&Vl[k][d4 * 4];
      acc0[d4*4+0] = fmaf(p0, vv.x, acc0[d4*4+0]);
      acc0[d4*4+1] = fmaf(p0, vv.y, acc0[d4*4+1]);
      acc0[d4*4+2] = fmaf(p0, vv.z, acc0[d4*4+2]);
      acc0[d4*4+3] = fmaf(p0, vv.w, acc0[d4*4+3]);
      acc1[d4*4+0] = fmaf(p1, vv.x, acc1[d4*4+0]);
      acc1[d4*4+1] = fmaf(p1, vv.y, acc1[d4*4+1]);
      acc1[d4*4+2] = fmaf(p1, vv.z, acc1[d4*4+2]);
      acc1[d4*4+3] = fmaf(p1, vv.w, acc1[d4*4+3]);
    }
  }
  const float w0 = 0.5f / l0, w1 = 0.5f / l1;
  if (mode == 0) {
    #pragma unroll
    for (int d4 = 0; d4 < 8; ++d4) {
      *(float4*)&outb[baseA + d4*4] = make_float4(acc0[d4*4+0]*w0, acc0[d4*4+1]*w0,
                                                  acc0[d4*4+2]*w0, acc0[d4*4+3]*w0);
      *(float4*)&outb[baseB + d4*4] = make_float4(acc1[d4*4+0]*w1, acc1[d4*4+1]*w1,
                                                  acc1[d4*4+2]*w1, acc1[d4*4+3]*w1);
    }
  } else {
    #pragma unroll
    for (int d4 = 0; d4 < 8; ++d4) {
      float4 a = *(const float4*)&outb[baseA + d4*4];
      a.x += acc0[d4*4+0]*w0; a.y += acc0[d4*4+1]*w0;
      a.z += acc0[d4*4+2]*w0; a.w += acc0[d4*4+3]*w0;
      *(float4*)&outb[baseA + d4*4] = a;
      float4 b = *(const float4*)&outb[baseB + d4*4];
      b.x += acc1[d4*4+0]*w1; b.y += acc1[d4*4+1]*w1;
      b.z += acc1[d4*4+2]*w1; b.w += acc1[d4*4+3]*w1;
      *(float4*)&outb[baseB + d4*4] = b;
    }
  }
}

// ---------------------------------------------------------------------------
// K3: out-proj + bias + residual + LayerNorm + mask, in place on d_out.
// grid 2048, block 256. 32 edges/block; thread = 4 edges x 4 cols microtile.
// Wo half-staged in LDS (32KB) + transposed att tile (8KB).
// ---------------------------------------------------------------------------
extern "C" __global__ __launch_bounds__(256) void k_final(
    float* __restrict__ outb, const float* __restrict__ ef,
    const float* __restrict__ Wo, const float* __restrict__ bo,
    const float* __restrict__ gam, const float* __restrict__ bet,
    const float* __restrict__ maskg)
{
  __shared__ float Wl[64 * 128];
  __shared__ float inT[64][32];   // [ic_local][edge_local]
  const int t = threadIdx.x;
  const int e0 = blockIdx.x * 32;
  const int cg = t & 31, eg = t >> 5;
  const int o0 = cg * 4;
  float acc[4][4] = {};
  for (int hc = 0; hc < 2; ++hc) {
    __syncthreads();
    for (int i = t * 4; i < 64 * 128; i += 1024)
      *(float4*)&Wl[i] = *(const float4*)&Wo[hc * 64 * 128 + i];
    {
      const int le = t >> 3, icb = (t & 7) * 8;
      const float* src = &outb[(size_t)(e0 + le) * CF + hc * 64 + icb];
      float4 v0 = *(const float4*)src;
      float4 v1 = *(const float4*)(src + 4);
      inT[icb + 0][le] = v0.x; inT[icb + 1][le] = v0.y;
      inT[icb + 2][le] = v0.z; inT[icb + 3][le] = v0.w;
      inT[icb + 4][le] = v1.x; inT[icb + 5][le] = v1.y;
      inT[icb + 6][le] = v1.z; inT[icb + 7][le] = v1.w;
    }
    __syncthreads();
    #pragma unroll 8
    for (int ic = 0; ic < 64; ++ic) {
      float4 a = *(const float4*)&inT[ic][eg * 4];
      float4 b = *(const float4*)&Wl[ic * 128 + o0];
      float av[4] = {a.x, a.y, a.z, a.w};
      float bv[4] = {b.x, b.y, b.z, b.w};
      #pragma unroll
      for (int i = 0; i < 4; ++i)
        #pragma unroll
        for (int j = 0; j < 4; ++j)
          acc[i][j] = fmaf(av[i], bv[j], acc[i][j]);
    }
  }
  float4 tb = *(const float4*)&bo[o0];
  float4 tg = *(const float4*)&gam[o0];
  float4 te = *(const float4*)&bet[o0];
  float bov[4] = {tb.x, tb.y, tb.z, tb.w};
  float gv[4]  = {tg.x, tg.y, tg.z, tg.w};
  float bev[4] = {te.x, te.y, te.z, te.w};
  float y[4][4];
  #pragma unroll
  for (int i = 0; i < 4; ++i) {
    const int e = e0 + eg * 4 + i;
    float4 r4 = *(const float4*)&ef[(size_t)e * CF + o0];
    float rv[4] = {r4.x, r4.y, r4.z, r4.w};
    float v[4];
    float s = 0.f, s2 = 0.f;
    #pragma unroll
    for (int j = 0; j < 4; ++j) {
      v[j] = acc[i][j] + bov[j] + rv[j];
      s += v[j]; s2 += v[j] * v[j];
    }
    #pragma unroll
    for (int mk = 1; mk <= 16; mk <<= 1) {
      s  += __shfl_xor(s,  mk, 64);
      s2 += __shfl_xor(s2, mk, 64);
    }
    const float mu = s * (1.f / 128.f);
    const float var = s2 * (1.f / 128.f) - mu * mu;
    const float rstd = rsqrtf(var + 1e-5f);
    const float mv = maskg[(size_t)(e >> 8) * NQ + (e & 255)];
    #pragma unroll
    for (int j = 0; j < 4; ++j)
      y[i][j] = ((v[j] - mu) * rstd * gv[j] + bev[j]) * mv;
  }
  #pragma unroll
  for (int i = 0; i < 4; ++i) {
    const int e = e0 + eg * 4 + i;
    *(float4*)&outb[(size_t)e * CF + o0] =
        make_float4(y[i][0], y[i][1], y[i][2], y[i][3]);
  }
}

// ---------------------------------------------------------------------------
extern "C" void kernel_launch(void* const* d_in, const int* in_sizes, int n_in,
                              void* d_out, int out_size, void* d_ws, size_t ws_size,
                              hipStream_t stream)
{
  (void)in_sizes; (void)n_in; (void)out_size; (void)ws_size;
  const float* ef   = (const float*)d_in[0];
  const float* mask = (const float*)d_in[1];
  const float* Wq   = (const float*)d_in[2];
  const float* Wk   = (const float*)d_in[3];
  const float* Wv   = (const float*)d_in[4];
  const float* Wo   = (const float*)d_in[5];
  const float* bo   = (const float*)d_in[6];
  const float* gam  = (const float*)d_in[7];
  const float* bet  = (const float*)d_in[8];
  float* out = (float*)d_out;
  float* Qb = (float*)d_ws;                       // 32MB
  float* Kb = Qb + (size_t)65536 * 128;           // 32MB
  float* Vb = Kb + (size_t)65536 * 128;           // 32MB  (needs 96MB ws)

  k_proj<<<dim3(2048, 3), dim3(256), 0, stream>>>(ef, Wq, Wk, Wv, Qb, Kb, Vb);
  k_attn<<<dim3(256, 4), dim3(128), 0, stream>>>(Qb, Kb, Vb, mask, out, 0);
  k_attn<<<dim3(256, 4), dim3(128), 0, stream>>>(Qb, Kb, Vb, mask, out, 1);
  k_final<<<dim3(2048), dim3(256), 0, stream>>>(out, ef, Wo, bo, gam, bet, mask);
}

// Round 4
// 230.140 us; speedup vs baseline: 3.2083x; 3.2083x over previous
//
#include <hip/hip_runtime.h>
#include <math.h>

#define NQ 256      // D (grid side)
#define CF 128      // channels
#define RS 0.17677669529663687f  // 1/sqrt(32)

typedef __attribute__((ext_vector_type(8))) short short8v;   // 8 bf16 = 4 VGPR
typedef __attribute__((ext_vector_type(4))) float f32x4;

static __device__ __forceinline__ unsigned short f2bf(float x) {
  union { float f; unsigned u; } v; v.f = x;
  unsigned r = v.u + 0x7FFFu + ((v.u >> 16) & 1u);  // RNE
  return (unsigned short)(r >> 16);
}

#define MFMA16(a, b, c) __builtin_amdgcn_mfma_f32_16x16x32_bf16(a, b, c, 0, 0, 0)

// ---------------------------------------------------------------------------
// K1: projection GEMM -> bf16 Q/K/V in edge-major (Nbuf) and transposed (Tbuf)
// layouts. grid (2048, 3) block 256. 32 edges x 128 cols, 4x4 microtile.
// Nbuf[e][ch] = P[e][ch];  Tbuf[(c*256 + r)][ch] = P[e=(r,c)][ch].
// Q scaled by 1/sqrt(HD).
// ---------------------------------------------------------------------------
extern "C" __global__ __launch_bounds__(256) void k_proj(
    const float* __restrict__ ef, const float* __restrict__ Wq,
    const float* __restrict__ Wk, const float* __restrict__ Wv,
    unsigned short* __restrict__ Qn, unsigned short* __restrict__ Kn,
    unsigned short* __restrict__ Vn, unsigned short* __restrict__ Qt,
    unsigned short* __restrict__ Kt, unsigned short* __restrict__ Vc)
{
  __shared__ float Wl[64 * 128];
  __shared__ float inT[64][32];
  const int y = blockIdx.y;
  const float* W = (y == 0) ? Wq : (y == 1) ? Wk : Wv;
  unsigned short* Nbuf = (y == 0) ? Qn : (y == 1) ? Kn : Vn;
  unsigned short* Tbuf = (y == 0) ? Qt : (y == 1) ? Kt : Vc;
  const float scale = (y == 0) ? RS : 1.0f;
  const int t = threadIdx.x;
  const int row0 = blockIdx.x * 32;
  const int cg = t & 31, rg = t >> 5;
  const int o0 = cg * 4, r0 = rg * 4;
  float acc[4][4] = {};
  for (int hc = 0; hc < 2; ++hc) {
    __syncthreads();
    for (int i = t * 4; i < 64 * 128; i += 1024)
      *(float4*)&Wl[i] = *(const float4*)&W[hc * 64 * 128 + i];
    {
      const int le = t >> 3, icb = (t & 7) * 8;
      const float* src = &ef[(size_t)(row0 + le) * CF + hc * 64 + icb];
      float4 v0 = *(const float4*)src;
      float4 v1 = *(const float4*)(src + 4);
      inT[icb + 0][le] = v0.x; inT[icb + 1][le] = v0.y;
      inT[icb + 2][le] = v0.z; inT[icb + 3][le] = v0.w;
      inT[icb + 4][le] = v1.x; inT[icb + 5][le] = v1.y;
      inT[icb + 6][le] = v1.z; inT[icb + 7][le] = v1.w;
    }
    __syncthreads();
    #pragma unroll 8
    for (int ic = 0; ic < 64; ++ic) {
      float4 a = *(const float4*)&inT[ic][r0];
      float4 b = *(const float4*)&Wl[ic * 128 + o0];
      float av[4] = {a.x, a.y, a.z, a.w};
      float bv[4] = {b.x, b.y, b.z, b.w};
      #pragma unroll
      for (int i = 0; i < 4; ++i)
        #pragma unroll
        for (int j = 0; j < 4; ++j)
          acc[i][j] = fmaf(av[i], bv[j], acc[i][j]);
    }
  }
  const int r_grid = row0 >> 8;
  #pragma unroll
  for (int i = 0; i < 4; ++i) {
    const int e = row0 + r0 + i;
    const int c = (row0 & 255) + r0 + i;
    unsigned short pk[4];
    #pragma unroll
    for (int j = 0; j < 4; ++j) pk[j] = f2bf(acc[i][j] * scale);
    const unsigned long long w64 =
        (unsigned long long)pk[0] | ((unsigned long long)pk[1] << 16) |
        ((unsigned long long)pk[2] << 32) | ((unsigned long long)pk[3] << 48);
    *(unsigned long long*)&Nbuf[(size_t)e * CF + o0] = w64;
    *(unsigned long long*)&Tbuf[((size_t)c * NQ + r_grid) * CF + o0] = w64;
  }
}

// ---------------------------------------------------------------------------
// K2: MFMA attention. Block = (slice cr, head h), 8 waves, wave w = q-chunk
// [w*32, w*32+32). Qs/Ks/Vs are pre-transposed bf16 slice-major buffers:
// slice row q/k contiguous 128 ch. mode 0: store 0.5*out; mode 1: accumulate.
// ---------------------------------------------------------------------------
extern "C" __global__ __launch_bounds__(512, 2) void k_attn(
    const unsigned short* __restrict__ Qs, const unsigned short* __restrict__ Ks,
    const unsigned short* __restrict__ Vs, const float* __restrict__ maskg,
    float* __restrict__ att, const int mode)
{
  __shared__ unsigned short Kl[256][40];   // [k][d] pad 8
  __shared__ unsigned short Vl[32][264];   // [d][k] pad 8
  __shared__ float biasl[256];
  __shared__ unsigned short Pb[8][32][40]; // per-wave P chunk [q][k] pad 8
  const int cr = blockIdx.x, h = blockIdx.y;
  const int t = threadIdx.x, w = t >> 6, l = t & 63;
  const int lr = l & 15, lg = l >> 4;

  const unsigned short* Kbase = Ks + (size_t)cr * (NQ * CF) + h * 32;
  const unsigned short* Vbase = Vs + (size_t)cr * (NQ * CF) + h * 32;
  {
    const int k = t >> 1, dh = t & 1;
    const unsigned short* srcK = Kbase + k * CF + dh * 16;
    short8v ka = *(const short8v*)srcK;
    short8v kb = *(const short8v*)(srcK + 8);
    *(short8v*)&Kl[k][dh * 16] = ka;
    *(short8v*)&Kl[k][dh * 16 + 8] = kb;
    const unsigned short* srcV = Vbase + k * CF + dh * 16;
    short8v va = *(const short8v*)srcV;
    short8v vb = *(const short8v*)(srcV + 8);
    #pragma unroll
    for (int i = 0; i < 8; ++i) Vl[dh * 16 + i][k] = (unsigned short)va[i];
    #pragma unroll
    for (int i = 0; i < 8; ++i) Vl[dh * 16 + 8 + i][k] = (unsigned short)vb[i];
  }
  if (t < 256) {
    const float mv = mode ? maskg[(size_t)cr * NQ + t] : maskg[(size_t)t * NQ + cr];
    biasl[t] = (mv == 0.f) ? -1e30f : 0.f;
  }
  // Q fragments (global, L2-resident)
  const unsigned short* Qbase = Qs + (size_t)cr * (NQ * CF) + h * 32;
  const int q0 = w * 32;
  short8v qf[2];
  qf[0] = *(const short8v*)(Qbase + (q0 + lr) * CF + lg * 8);
  qf[1] = *(const short8v*)(Qbase + (q0 + 16 + lr) * CF + lg * 8);
  __syncthreads();

  // ---- QK^T: S[2 qt][16 kt] D-frags (f32), bias added, running col-max ----
  f32x4 S[2][16];
  float pmax[2][4];
  #pragma unroll
  for (int qt = 0; qt < 2; ++qt)
    #pragma unroll
    for (int r = 0; r < 4; ++r) pmax[qt][r] = -INFINITY;
  #pragma unroll
  for (int kt = 0; kt < 16; ++kt) {
    short8v kf = *(const short8v*)&Kl[kt * 16 + lr][lg * 8];
    const float bias = biasl[kt * 16 + lr];
    #pragma unroll
    for (int qt = 0; qt < 2; ++qt) {
      f32x4 z = {0.f, 0.f, 0.f, 0.f};
      f32x4 s = MFMA16(qf[qt], kf, z);
      #pragma unroll
      for (int r = 0; r < 4; ++r) {
        s[r] += bias;
        pmax[qt][r] = fmaxf(pmax[qt][r], s[r]);
      }
      S[qt][kt] = s;
    }
  }
  // row-max across the 16 col-lanes
  #pragma unroll
  for (int qt = 0; qt < 2; ++qt)
    #pragma unroll
    for (int r = 0; r < 4; ++r) {
      float m = pmax[qt][r];
      m = fmaxf(m, __shfl_xor(m, 1));
      m = fmaxf(m, __shfl_xor(m, 2));
      m = fmaxf(m, __shfl_xor(m, 4));
      m = fmaxf(m, __shfl_xor(m, 8));
      pmax[qt][r] = m;
    }

  // ---- softmax + PV per 32-k chunk ----
  f32x4 out[2][2];
  #pragma unroll
  for (int qt = 0; qt < 2; ++qt)
    #pragma unroll
    for (int dt = 0; dt < 2; ++dt) out[qt][dt] = (f32x4){0.f, 0.f, 0.f, 0.f};
  float psum[2][4] = {};
  #pragma unroll
  for (int kc = 0; kc < 8; ++kc) {
    #pragma unroll
    for (int kth = 0; kth < 2; ++kth) {
      const int kt = kc * 2 + kth;
      #pragma unroll
      for (int qt = 0; qt < 2; ++qt) {
        f32x4 s = S[qt][kt];
        #pragma unroll
        for (int r = 0; r < 4; ++r) {
          const float p = __expf(s[r] - pmax[qt][r]);
          psum[qt][r] += p;
          Pb[w][qt * 16 + lg * 4 + r][kth * 16 + lr] = f2bf(p);
        }
      }
    }
    asm volatile("s_waitcnt lgkmcnt(0)" ::: "memory");
    short8v vf[2];
    #pragma unroll
    for (int dt = 0; dt < 2; ++dt)
      vf[dt] = *(const short8v*)&Vl[dt * 16 + lr][kc * 32 + lg * 8];
    #pragma unroll
    for (int qt = 0; qt < 2; ++qt) {
      short8v pf = *(const short8v*)&Pb[w][qt * 16 + lr][lg * 8];
      #pragma unroll
      for (int dt = 0; dt < 2; ++dt)
        out[qt][dt] = MFMA16(pf, vf[dt], out[qt][dt]);
    }
  }

  // ---- normalize by 0.5/rowsum and store ----
  #pragma unroll
  for (int qt = 0; qt < 2; ++qt) {
    float inv[4];
    #pragma unroll
    for (int r = 0; r < 4; ++r) {
      float ssum = psum[qt][r];
      ssum += __shfl_xor(ssum, 1);
      ssum += __shfl_xor(ssum, 2);
      ssum += __shfl_xor(ssum, 4);
      ssum += __shfl_xor(ssum, 8);
      inv[r] = 0.5f / ssum;
    }
    #pragma unroll
    for (int dt = 0; dt < 2; ++dt)
      #pragma unroll
      for (int r = 0; r < 4; ++r) {
        const int q = q0 + qt * 16 + lg * 4 + r;
        const size_t edge = mode ? ((size_t)cr * NQ + q) : ((size_t)q * NQ + cr);
        float* p = att + edge * CF + h * 32 + dt * 16 + lr;
        const float v = out[qt][dt][r] * inv[r];
        if (mode) *p += v; else *p = v;
      }
  }
}

// ---------------------------------------------------------------------------
// K3: out-proj + bias + residual + LayerNorm + mask, in place on d_out.
// ---------------------------------------------------------------------------
extern "C" __global__ __launch_bounds__(256) void k_final(
    float* __restrict__ outb, const float* __restrict__ ef,
    const float* __restrict__ Wo, const float* __restrict__ bo,
    const float* __restrict__ gam, const float* __restrict__ bet,
    const float* __restrict__ maskg)
{
  __shared__ float Wl[64 * 128];
  __shared__ float inT[64][32];
  const int t = threadIdx.x;
  const int e0 = blockIdx.x * 32;
  const int cg = t & 31, eg = t >> 5;
  const int o0 = cg * 4;
  float acc[4][4] = {};
  for (int hc = 0; hc < 2; ++hc) {
    __syncthreads();
    for (int i = t * 4; i < 64 * 128; i += 1024)
      *(float4*)&Wl[i] = *(const float4*)&Wo[hc * 64 * 128 + i];
    {
      const int le = t >> 3, icb = (t & 7) * 8;
      const float* src = &outb[(size_t)(e0 + le) * CF + hc * 64 + icb];
      float4 v0 = *(const float4*)src;
      float4 v1 = *(const float4*)(src + 4);
      inT[icb + 0][le] = v0.x; inT[icb + 1][le] = v0.y;
      inT[icb + 2][le] = v0.z; inT[icb + 3][le] = v0.w;
      inT[icb + 4][le] = v1.x; inT[icb + 5][le] = v1.y;
      inT[icb + 6][le] = v1.z; inT[icb + 7][le] = v1.w;
    }
    __syncthreads();
    #pragma unroll 8
    for (int ic = 0; ic < 64; ++ic) {
      float4 a = *(const float4*)&inT[ic][eg * 4];
      float4 b = *(const float4*)&Wl[ic * 128 + o0];
      float av[4] = {a.x, a.y, a.z, a.w};
      float bv[4] = {b.x, b.y, b.z, b.w};
      #pragma unroll
      for (int i = 0; i < 4; ++i)
        #pragma unroll
        for (int j = 0; j < 4; ++j)
          acc[i][j] = fmaf(av[i], bv[j], acc[i][j]);
    }
  }
  float4 tb = *(const float4*)&bo[o0];
  float4 tg = *(const float4*)&gam[o0];
  float4 te = *(const float4*)&bet[o0];
  float bov[4] = {tb.x, tb.y, tb.z, tb.w};
  float gv[4]  = {tg.x, tg.y, tg.z, tg.w};
  float bev[4] = {te.x, te.y, te.z, te.w};
  float y[4][4];
  #pragma unroll
  for (int i = 0; i < 4; ++i) {
    const int e = e0 + eg * 4 + i;
    float4 r4 = *(const float4*)&ef[(size_t)e * CF + o0];
    float rv[4] = {r4.x, r4.y, r4.z, r4.w};
    float v[4];
    float s = 0.f, s2 = 0.f;
    #pragma unroll
    for (int j = 0; j < 4; ++j) {
      v[j] = acc[i][j] + bov[j] + rv[j];
      s += v[j]; s2 += v[j] * v[j];
    }
    #pragma unroll
    for (int mk = 1; mk <= 16; mk <<= 1) {
      s  += __shfl_xor(s,  mk, 64);
      s2 += __shfl_xor(s2, mk, 64);
    }
    const float mu = s * (1.f / 128.f);
    const float var = s2 * (1.f / 128.f) - mu * mu;
    const float rstd = rsqrtf(var + 1e-5f);
    const float mv = maskg[(size_t)(e >> 8) * NQ + (e & 255)];
    #pragma unroll
    for (int j = 0; j < 4; ++j)
      y[i][j] = ((v[j] - mu) * rstd * gv[j] + bev[j]) * mv;
  }
  #pragma unroll
  for (int i = 0; i < 4; ++i) {
    const int e = e0 + eg * 4 + i;
    *(float4*)&outb[(size_t)e * CF + o0] =
        make_float4(y[i][0], y[i][1], y[i][2], y[i][3]);
  }
}

// ---------------------------------------------------------------------------
extern "C" void kernel_launch(void* const* d_in, const int* in_sizes, int n_in,
                              void* d_out, int out_size, void* d_ws, size_t ws_size,
                              hipStream_t stream)
{
  (void)in_sizes; (void)n_in; (void)out_size; (void)ws_size;
  const float* ef   = (const float*)d_in[0];
  const float* mask = (const float*)d_in[1];
  const float* Wq   = (const float*)d_in[2];
  const float* Wk   = (const float*)d_in[3];
  const float* Wv   = (const float*)d_in[4];
  const float* Wo   = (const float*)d_in[5];
  const float* bo   = (const float*)d_in[6];
  const float* gam  = (const float*)d_in[7];
  const float* bet  = (const float*)d_in[8];
  float* out = (float*)d_out;
  const size_t BUF = (size_t)65536 * 128;   // 8M bf16 elements = 16MB
  unsigned short* Qn = (unsigned short*)d_ws;
  unsigned short* Kn = Qn + BUF;
  unsigned short* Vn = Kn + BUF;
  unsigned short* Qt = Vn + BUF;
  unsigned short* Kt = Qt + BUF;
  unsigned short* Vc = Kt + BUF;             // total 96MB

  k_proj<<<dim3(2048, 3), dim3(256), 0, stream>>>(ef, Wq, Wk, Wv,
                                                  Qn, Kn, Vn, Qt, Kt, Vc);
  k_attn<<<dim3(256, 4), dim3(512), 0, stream>>>(Qt, Kt, Vc, mask, out, 0);
  k_attn<<<dim3(256, 4), dim3(512), 0, stream>>>(Qn, Kn, Vn, mask, out, 1);
  k_final<<<dim3(2048), dim3(256), 0, stream>>>(out, ef, Wo, bo, gam, bet, mask);
}

// Round 5
// 207.919 us; speedup vs baseline: 3.5512x; 1.1069x over previous
//
#include <hip/hip_runtime.h>
#include <math.h>

#define NQ 256      // D (grid side)
#define CF 128      // channels
#define RS 0.17677669529663687f  // 1/sqrt(32)

typedef __attribute__((ext_vector_type(8))) short short8v;   // 8 bf16 = 4 VGPR
typedef __attribute__((ext_vector_type(4))) float f32x4;

static __device__ __forceinline__ unsigned short f2bf(float x) {
  union { float f; unsigned u; } v; v.f = x;
  unsigned r = v.u + 0x7FFFu + ((v.u >> 16) & 1u);  // RNE
  return (unsigned short)(r >> 16);
}

static __device__ __forceinline__ short8v cvt8(float4 a, float4 b) {
  short8v r;
  r[0] = (short)f2bf(a.x); r[1] = (short)f2bf(a.y);
  r[2] = (short)f2bf(a.z); r[3] = (short)f2bf(a.w);
  r[4] = (short)f2bf(b.x); r[5] = (short)f2bf(b.y);
  r[6] = (short)f2bf(b.z); r[7] = (short)f2bf(b.w);
  return r;
}

#define MFMA16(a, b, c) __builtin_amdgcn_mfma_f32_16x16x32_bf16(a, b, c, 0, 0, 0)

// ---------------------------------------------------------------------------
// K0: weight prep. Wt[y][n][k] = bf16(W_y[k][n]), y in {q,k,v,o}. RS folded
// into Wq. grid 4 x 256.
// ---------------------------------------------------------------------------
extern "C" __global__ __launch_bounds__(256) void k_cvt(
    const float* __restrict__ Wq, const float* __restrict__ Wk,
    const float* __restrict__ Wv, const float* __restrict__ Wo,
    unsigned short* __restrict__ Wt)
{
  const int y = blockIdx.x;
  const float* W = (y == 0) ? Wq : (y == 1) ? Wk : (y == 2) ? Wv : Wo;
  unsigned short* dst = Wt + (size_t)y * 16384;
  const float sc = (y == 0) ? RS : 1.0f;
  const int t = threadIdx.x;
  #pragma unroll
  for (int i = 0; i < 16; ++i) {
    const int flat = (t + 256 * i) * 4;
    const int k = flat >> 7, n = flat & 127;
    float4 v = *(const float4*)&W[flat];
    dst[(n + 0) * 128 + k] = f2bf(v.x * sc);
    dst[(n + 1) * 128 + k] = f2bf(v.y * sc);
    dst[(n + 2) * 128 + k] = f2bf(v.z * sc);
    dst[(n + 3) * 128 + k] = f2bf(v.w * sc);
  }
}

// ---------------------------------------------------------------------------
// K1: MFMA projection. grid 1024, block 512 (8 waves). Block = 64 edges x
// 128 N x 3 weights. Wave w: rows (w&3)*16, N-half (w>>2)*64.
// A-frags direct from global ef f32 (converted); B-frags from Wt (L2).
// Output via LDS re-layout -> coalesced bf16 stores to Nbuf + Tbuf.
// ---------------------------------------------------------------------------
extern "C" __global__ __launch_bounds__(512) void k_projM(
    const float* __restrict__ ef, const unsigned short* __restrict__ Wt,
    unsigned short* __restrict__ Qn, unsigned short* __restrict__ Kn,
    unsigned short* __restrict__ Vn, unsigned short* __restrict__ Qt,
    unsigned short* __restrict__ Kt, unsigned short* __restrict__ Vc)
{
  __shared__ unsigned short ol[64][136];
  const int t = threadIdx.x, w = t >> 6, l = t & 63;
  const int lr = l & 15, lg = l >> 4;
  const int e0 = blockIdx.x * 64;
  const int sr = (w & 3) * 16, nh = (w >> 2) * 64;

  // A-fragments: ef row e0+sr+lr, 8 f32 per kg, converted to bf16
  short8v af[4];
  const float* arow = ef + (size_t)(e0 + sr + lr) * CF;
  #pragma unroll
  for (int kg = 0; kg < 4; ++kg) {
    float4 a = *(const float4*)&arow[kg * 32 + lg * 8];
    float4 b = *(const float4*)&arow[kg * 32 + lg * 8 + 4];
    af[kg] = cvt8(a, b);
  }

  f32x4 acc[3][4];
  #pragma unroll
  for (int y = 0; y < 3; ++y)
    #pragma unroll
    for (int nt = 0; nt < 4; ++nt) acc[y][nt] = (f32x4){0.f, 0.f, 0.f, 0.f};

  #pragma unroll
  for (int y = 0; y < 3; ++y) {
    const unsigned short* Wy = Wt + (size_t)y * 16384;
    #pragma unroll
    for (int nt = 0; nt < 4; ++nt) {
      const unsigned short* wrow = Wy + (size_t)(nh + nt * 16 + lr) * 128;
      #pragma unroll
      for (int kg = 0; kg < 4; ++kg) {
        short8v bf = *(const short8v*)&wrow[kg * 32 + lg * 8];
        acc[y][nt] = MFMA16(af[kg], bf, acc[y][nt]);
      }
    }
  }

  const int rg = e0 >> 8, c0 = e0 & 255;
  #pragma unroll
  for (int y = 0; y < 3; ++y) {
    __syncthreads();   // previous iteration's LDS reads complete
    #pragma unroll
    for (int nt = 0; nt < 4; ++nt)
      #pragma unroll
      for (int r = 0; r < 4; ++r)
        ol[sr + lg * 4 + r][nh + nt * 16 + lr] = f2bf(acc[y][nt][r]);
    __syncthreads();
    unsigned short* Nb = (y == 0) ? Qn : (y == 1) ? Kn : Vn;
    unsigned short* Tb = (y == 0) ? Qt : (y == 1) ? Kt : Vc;
    const int row = t >> 3, cb = (t & 7) * 16;
    short8v v0 = *(const short8v*)&ol[row][cb];
    short8v v1 = *(const short8v*)&ol[row][cb + 8];
    const size_t ne = (size_t)(e0 + row) * CF + cb;
    *(short8v*)&Nb[ne] = v0;
    *(short8v*)&Nb[ne + 8] = v1;
    const size_t te = ((size_t)(c0 + row) * NQ + rg) * CF + cb;
    *(short8v*)&Tb[te] = v0;
    *(short8v*)&Tb[te + 8] = v1;
  }
}

// ---------------------------------------------------------------------------
// K2: MFMA attention (unchanged from round 4). Block = (slice cr, head h),
// 8 waves. mode 0: store 0.5*out; mode 1: accumulate.
// ---------------------------------------------------------------------------
extern "C" __global__ __launch_bounds__(512, 2) void k_attn(
    const unsigned short* __restrict__ Qs, const unsigned short* __restrict__ Ks,
    const unsigned short* __restrict__ Vs, const float* __restrict__ maskg,
    float* __restrict__ att, const int mode)
{
  __shared__ unsigned short Kl[256][40];   // [k][d] pad 8
  __shared__ unsigned short Vl[32][264];   // [d][k] pad 8
  __shared__ float biasl[256];
  __shared__ unsigned short Pb[8][32][40]; // per-wave P chunk [q][k] pad 8
  const int cr = blockIdx.x, h = blockIdx.y;
  const int t = threadIdx.x, w = t >> 6, l = t & 63;
  const int lr = l & 15, lg = l >> 4;

  const unsigned short* Kbase = Ks + (size_t)cr * (NQ * CF) + h * 32;
  const unsigned short* Vbase = Vs + (size_t)cr * (NQ * CF) + h * 32;
  {
    const int k = t >> 1, dh = t & 1;
    const unsigned short* srcK = Kbase + k * CF + dh * 16;
    short8v ka = *(const short8v*)srcK;
    short8v kb = *(const short8v*)(srcK + 8);
    *(short8v*)&Kl[k][dh * 16] = ka;
    *(short8v*)&Kl[k][dh * 16 + 8] = kb;
    const unsigned short* srcV = Vbase + k * CF + dh * 16;
    short8v va = *(const short8v*)srcV;
    short8v vb = *(const short8v*)(srcV + 8);
    #pragma unroll
    for (int i = 0; i < 8; ++i) Vl[dh * 16 + i][k] = (unsigned short)va[i];
    #pragma unroll
    for (int i = 0; i < 8; ++i) Vl[dh * 16 + 8 + i][k] = (unsigned short)vb[i];
  }
  if (t < 256) {
    const float mv = mode ? maskg[(size_t)cr * NQ + t] : maskg[(size_t)t * NQ + cr];
    biasl[t] = (mv == 0.f) ? -1e30f : 0.f;
  }
  const unsigned short* Qbase = Qs + (size_t)cr * (NQ * CF) + h * 32;
  const int q0 = w * 32;
  short8v qf[2];
  qf[0] = *(const short8v*)(Qbase + (q0 + lr) * CF + lg * 8);
  qf[1] = *(const short8v*)(Qbase + (q0 + 16 + lr) * CF + lg * 8);
  __syncthreads();

  f32x4 S[2][16];
  float pmax[2][4];
  #pragma unroll
  for (int qt = 0; qt < 2; ++qt)
    #pragma unroll
    for (int r = 0; r < 4; ++r) pmax[qt][r] = -INFINITY;
  #pragma unroll
  for (int kt = 0; kt < 16; ++kt) {
    short8v kf = *(const short8v*)&Kl[kt * 16 + lr][lg * 8];
    const float bias = biasl[kt * 16 + lr];
    #pragma unroll
    for (int qt = 0; qt < 2; ++qt) {
      f32x4 z = {0.f, 0.f, 0.f, 0.f};
      f32x4 s = MFMA16(qf[qt], kf, z);
      #pragma unroll
      for (int r = 0; r < 4; ++r) {
        s[r] += bias;
        pmax[qt][r] = fmaxf(pmax[qt][r], s[r]);
      }
      S[qt][kt] = s;
    }
  }
  #pragma unroll
  for (int qt = 0; qt < 2; ++qt)
    #pragma unroll
    for (int r = 0; r < 4; ++r) {
      float m = pmax[qt][r];
      m = fmaxf(m, __shfl_xor(m, 1));
      m = fmaxf(m, __shfl_xor(m, 2));
      m = fmaxf(m, __shfl_xor(m, 4));
      m = fmaxf(m, __shfl_xor(m, 8));
      pmax[qt][r] = m;
    }

  f32x4 out[2][2];
  #pragma unroll
  for (int qt = 0; qt < 2; ++qt)
    #pragma unroll
    for (int dt = 0; dt < 2; ++dt) out[qt][dt] = (f32x4){0.f, 0.f, 0.f, 0.f};
  float psum[2][4] = {};
  #pragma unroll
  for (int kc = 0; kc < 8; ++kc) {
    #pragma unroll
    for (int kth = 0; kth < 2; ++kth) {
      const int kt = kc * 2 + kth;
      #pragma unroll
      for (int qt = 0; qt < 2; ++qt) {
        f32x4 s = S[qt][kt];
        #pragma unroll
        for (int r = 0; r < 4; ++r) {
          const float p = __expf(s[r] - pmax[qt][r]);
          psum[qt][r] += p;
          Pb[w][qt * 16 + lg * 4 + r][kth * 16 + lr] = f2bf(p);
        }
      }
    }
    asm volatile("s_waitcnt lgkmcnt(0)" ::: "memory");
    short8v vf[2];
    #pragma unroll
    for (int dt = 0; dt < 2; ++dt)
      vf[dt] = *(const short8v*)&Vl[dt * 16 + lr][kc * 32 + lg * 8];
    #pragma unroll
    for (int qt = 0; qt < 2; ++qt) {
      short8v pf = *(const short8v*)&Pb[w][qt * 16 + lr][lg * 8];
      #pragma unroll
      for (int dt = 0; dt < 2; ++dt)
        out[qt][dt] = MFMA16(pf, vf[dt], out[qt][dt]);
    }
  }

  #pragma unroll
  for (int qt = 0; qt < 2; ++qt) {
    float inv[4];
    #pragma unroll
    for (int r = 0; r < 4; ++r) {
      float ssum = psum[qt][r];
      ssum += __shfl_xor(ssum, 1);
      ssum += __shfl_xor(ssum, 2);
      ssum += __shfl_xor(ssum, 4);
      ssum += __shfl_xor(ssum, 8);
      inv[r] = 0.5f / ssum;
    }
    #pragma unroll
    for (int dt = 0; dt < 2; ++dt)
      #pragma unroll
      for (int r = 0; r < 4; ++r) {
        const int q = q0 + qt * 16 + lg * 4 + r;
        const size_t edge = mode ? ((size_t)cr * NQ + q) : ((size_t)q * NQ + cr);
        float* p = att + edge * CF + h * 32 + dt * 16 + lr;
        const float v = out[qt][dt][r] * inv[r];
        if (mode) *p += v; else *p = v;
      }
  }
}

// ---------------------------------------------------------------------------
// K3: MFMA out-proj + bias + residual + LayerNorm + mask, in place on d_out.
// grid 1024, block 256 (4 waves). Wave = 16 edges x 128 N. LN reduced in
// D-frag registers via shfl_xor over the 16 col-lanes.
// ---------------------------------------------------------------------------
extern "C" __global__ __launch_bounds__(256) void k_finalM(
    float* __restrict__ outb, const float* __restrict__ ef,
    const unsigned short* __restrict__ Wot, const float* __restrict__ bo,
    const float* __restrict__ gam, const float* __restrict__ bet,
    const float* __restrict__ maskg)
{
  const int t = threadIdx.x, w = t >> 6, l = t & 63;
  const int lr = l & 15, lg = l >> 4;
  const int e0 = blockIdx.x * 64 + w * 16;   // wave strip base

  short8v af[4];
  const float* arow = outb + (size_t)(e0 + lr) * CF;
  #pragma unroll
  for (int kg = 0; kg < 4; ++kg) {
    float4 a = *(const float4*)&arow[kg * 32 + lg * 8];
    float4 b = *(const float4*)&arow[kg * 32 + lg * 8 + 4];
    af[kg] = cvt8(a, b);
  }

  f32x4 acc[8];
  #pragma unroll
  for (int nt = 0; nt < 8; ++nt) acc[nt] = (f32x4){0.f, 0.f, 0.f, 0.f};
  #pragma unroll
  for (int nt = 0; nt < 8; ++nt) {
    const unsigned short* wrow = Wot + (size_t)(nt * 16 + lr) * 128;
    #pragma unroll
    for (int kg = 0; kg < 4; ++kg) {
      short8v bf = *(const short8v*)&wrow[kg * 32 + lg * 8];
      acc[nt] = MFMA16(af[kg], bf, acc[nt]);
    }
  }

  float bo_l[8], g_l[8], be_l[8];
  #pragma unroll
  for (int nt = 0; nt < 8; ++nt) {
    bo_l[nt] = bo[nt * 16 + lr];
    g_l[nt]  = gam[nt * 16 + lr];
    be_l[nt] = bet[nt * 16 + lr];
  }

  float s[4] = {}, s2[4] = {};
  #pragma unroll
  for (int nt = 0; nt < 8; ++nt)
    #pragma unroll
    for (int r = 0; r < 4; ++r) {
      const float res = ef[(size_t)(e0 + lg * 4 + r) * CF + nt * 16 + lr];
      const float v = acc[nt][r] + bo_l[nt] + res;
      acc[nt][r] = v;
      s[r] += v; s2[r] += v * v;
    }
  float mu[4], rstd[4], mk[4];
  #pragma unroll
  for (int r = 0; r < 4; ++r) {
    float a = s[r], b = s2[r];
    a += __shfl_xor(a, 1); b += __shfl_xor(b, 1);
    a += __shfl_xor(a, 2); b += __shfl_xor(b, 2);
    a += __shfl_xor(a, 4); b += __shfl_xor(b, 4);
    a += __shfl_xor(a, 8); b += __shfl_xor(b, 8);
    mu[r] = a * (1.f / 128.f);
    const float var = b * (1.f / 128.f) - mu[r] * mu[r];
    rstd[r] = rsqrtf(var + 1e-5f);
    mk[r] = maskg[e0 + lg * 4 + r];
  }
  #pragma unroll
  for (int nt = 0; nt < 8; ++nt)
    #pragma unroll
    for (int r = 0; r < 4; ++r) {
      const float yv = ((acc[nt][r] - mu[r]) * rstd[r] * g_l[nt] + be_l[nt]) * mk[r];
      outb[(size_t)(e0 + lg * 4 + r) * CF + nt * 16 + lr] = yv;
    }
}

// ---------------------------------------------------------------------------
extern "C" void kernel_launch(void* const* d_in, const int* in_sizes, int n_in,
                              void* d_out, int out_size, void* d_ws, size_t ws_size,
                              hipStream_t stream)
{
  (void)in_sizes; (void)n_in; (void)out_size; (void)ws_size;
  const float* ef   = (const float*)d_in[0];
  const float* mask = (const float*)d_in[1];
  const float* Wq   = (const float*)d_in[2];
  const float* Wk   = (const float*)d_in[3];
  const float* Wv   = (const float*)d_in[4];
  const float* Wo   = (const float*)d_in[5];
  const float* bo   = (const float*)d_in[6];
  const float* gam  = (const float*)d_in[7];
  const float* bet  = (const float*)d_in[8];
  float* out = (float*)d_out;
  const size_t BUF = (size_t)65536 * 128;       // 8M bf16 elems = 16MB
  unsigned short* Wt = (unsigned short*)d_ws;   // 4 x 16384 = 128KB
  unsigned short* Qn = Wt + 4 * 16384;
  unsigned short* Kn = Qn + BUF;
  unsigned short* Vn = Kn + BUF;
  unsigned short* Qt = Vn + BUF;
  unsigned short* Kt = Qt + BUF;
  unsigned short* Vc = Kt + BUF;                // total ~96.1MB

  k_cvt<<<dim3(4), dim3(256), 0, stream>>>(Wq, Wk, Wv, Wo, Wt);
  k_projM<<<dim3(1024), dim3(512), 0, stream>>>(ef, Wt, Qn, Kn, Vn, Qt, Kt, Vc);
  k_attn<<<dim3(256, 4), dim3(512), 0, stream>>>(Qt, Kt, Vc, mask, out, 0);
  k_attn<<<dim3(256, 4), dim3(512), 0, stream>>>(Qn, Kn, Vn, mask, out, 1);
  k_finalM<<<dim3(1024), dim3(256), 0, stream>>>(out, ef, Wt + 3 * 16384,
                                                 bo, gam, bet, mask);
}

// Round 6
// 144.262 us; speedup vs baseline: 5.1182x; 1.4413x over previous
//
#include <hip/hip_runtime.h>
#include <math.h>

#define NQ 256      // D (grid side)
#define CF 128      // channels
#define RS 0.17677669529663687f  // 1/sqrt(32)

typedef __attribute__((ext_vector_type(8))) short short8v;   // 8 bf16 = 4 VGPR
typedef __attribute__((ext_vector_type(4))) float f32x4;

static __device__ __forceinline__ unsigned short f2bf(float x) {
  union { float f; unsigned u; } v; v.f = x;
  unsigned r = v.u + 0x7FFFu + ((v.u >> 16) & 1u);  // RNE
  return (unsigned short)(r >> 16);
}

static __device__ __forceinline__ short8v cvt8(float4 a, float4 b) {
  short8v r;
  r[0] = (short)f2bf(a.x); r[1] = (short)f2bf(a.y);
  r[2] = (short)f2bf(a.z); r[3] = (short)f2bf(a.w);
  r[4] = (short)f2bf(b.x); r[5] = (short)f2bf(b.y);
  r[6] = (short)f2bf(b.z); r[7] = (short)f2bf(b.w);
  return r;
}

#define MFMA16(a, b, c) __builtin_amdgcn_mfma_f32_16x16x32_bf16(a, b, c, 0, 0, 0)

// ---------------------------------------------------------------------------
// K0: weight prep. Wt[y][n][k] = bf16(W_y[k][n]), y in {q,k,v,o}. RS folded
// into Wq. grid 4 x 256.
// ---------------------------------------------------------------------------
extern "C" __global__ __launch_bounds__(256) void k_cvt(
    const float* __restrict__ Wq, const float* __restrict__ Wk,
    const float* __restrict__ Wv, const float* __restrict__ Wo,
    unsigned short* __restrict__ Wt)
{
  const int y = blockIdx.x;
  const float* W = (y == 0) ? Wq : (y == 1) ? Wk : (y == 2) ? Wv : Wo;
  unsigned short* dst = Wt + (size_t)y * 16384;
  const float sc = (y == 0) ? RS : 1.0f;
  const int t = threadIdx.x;
  #pragma unroll
  for (int i = 0; i < 16; ++i) {
    const int flat = (t + 256 * i) * 4;
    const int k = flat >> 7, n = flat & 127;
    float4 v = *(const float4*)&W[flat];
    dst[(n + 0) * 128 + k] = f2bf(v.x * sc);
    dst[(n + 1) * 128 + k] = f2bf(v.y * sc);
    dst[(n + 2) * 128 + k] = f2bf(v.z * sc);
    dst[(n + 3) * 128 + k] = f2bf(v.w * sc);
  }
}

// ---------------------------------------------------------------------------
// K1: MFMA projection -> edge-major bf16 Q/K/V only. grid 2048, block 256
// (4 independent waves, no barriers). Wave g = blk*4+w handles a 16-edge
// strip x 64-N half x 3 weights. Per-wave LDS stash coalesces the stores.
// ---------------------------------------------------------------------------
extern "C" __global__ __launch_bounds__(256) void k_projM(
    const float* __restrict__ ef, const unsigned short* __restrict__ Wt,
    unsigned short* __restrict__ Qn, unsigned short* __restrict__ Kn,
    unsigned short* __restrict__ Vn)
{
  __shared__ unsigned short olw[4][16][72];
  const int t = threadIdx.x, w = t >> 6, l = t & 63;
  const int lr = l & 15, lg = l >> 4;
  const int g = blockIdx.x * 4 + w;
  const int es = (g >> 1) * 16;     // edge strip base
  const int nh = (g & 1) * 64;      // N half

  short8v af[4];
  const float* arow = ef + (size_t)(es + lr) * CF;
  #pragma unroll
  for (int kg = 0; kg < 4; ++kg) {
    float4 a = *(const float4*)&arow[kg * 32 + lg * 8];
    float4 b = *(const float4*)&arow[kg * 32 + lg * 8 + 4];
    af[kg] = cvt8(a, b);
  }

  #pragma unroll
  for (int y = 0; y < 3; ++y) {
    f32x4 acc[4];
    #pragma unroll
    for (int nt = 0; nt < 4; ++nt) acc[nt] = (f32x4){0.f, 0.f, 0.f, 0.f};
    const unsigned short* Wy = Wt + (size_t)y * 16384;
    #pragma unroll
    for (int nt = 0; nt < 4; ++nt) {
      const unsigned short* wrow = Wy + (size_t)(nh + nt * 16 + lr) * 128;
      #pragma unroll
      for (int kg = 0; kg < 4; ++kg) {
        short8v bf = *(const short8v*)&wrow[kg * 32 + lg * 8];
        acc[nt] = MFMA16(af[kg], bf, acc[nt]);
      }
    }
    // stash D-frags (wave-local, in-order LDS => lgkmcnt-only sync)
    #pragma unroll
    for (int nt = 0; nt < 4; ++nt)
      #pragma unroll
      for (int r = 0; r < 4; ++r)
        olw[w][lg * 4 + r][nt * 16 + lr] = f2bf(acc[nt][r]);
    asm volatile("s_waitcnt lgkmcnt(0)" ::: "memory");
    short8v v0 = *(const short8v*)&olw[w][l >> 2][(l & 3) * 16];
    short8v v1 = *(const short8v*)&olw[w][l >> 2][(l & 3) * 16 + 8];
    asm volatile("s_waitcnt lgkmcnt(0)" ::: "memory");
    unsigned short* Nb = (y == 0) ? Qn : (y == 1) ? Kn : Vn;
    const size_t ne = (size_t)(es + (l >> 2)) * CF + nh + (l & 3) * 16;
    *(short8v*)&Nb[ne] = v0;
    *(short8v*)&Nb[ne + 8] = v1;
  }
}

// ---------------------------------------------------------------------------
// K2: MFMA attention, both modes in one launch. Block = (slice cr, head h,
// mode z). 8 waves x 32 q. Sources are edge-major Q/K/V: mode 0 gathers
// column-slice rows (L3-resident), mode 1 reads linear. No-max softmax
// (S ~ N(0,1); masked keys -> exp(-1e30) = 0). Output bf16 head-major
// att[h][edge][32], 0.5/rowsum folded.
// ---------------------------------------------------------------------------
extern "C" __global__ __launch_bounds__(512, 2) void k_attn(
    const unsigned short* __restrict__ Qn, const unsigned short* __restrict__ Kn,
    const unsigned short* __restrict__ Vn, const float* __restrict__ maskg,
    unsigned short* __restrict__ att0, unsigned short* __restrict__ att1)
{
  __shared__ unsigned short Kl[256][40];   // [k][d] pad 8
  __shared__ unsigned short Vl[32][264];   // [d][k] pad 8
  __shared__ float biasl[256];
  __shared__ unsigned short Pb[8][32][40]; // per-wave P chunk [q][k] pad 8
  const int cr = blockIdx.x, h = blockIdx.y, mode = blockIdx.z;
  const int t = threadIdx.x, w = t >> 6, l = t & 63;
  const int lr = l & 15, lg = l >> 4;

  {
    const int k = t >> 1, dh = t & 1;
    const size_t eb = (mode ? ((size_t)cr * NQ + k) : ((size_t)k * NQ + cr)) * CF
                      + h * 32 + dh * 16;
    short8v ka = *(const short8v*)(Kn + eb);
    short8v kb = *(const short8v*)(Kn + eb + 8);
    *(short8v*)&Kl[k][dh * 16] = ka;
    *(short8v*)&Kl[k][dh * 16 + 8] = kb;
    short8v va = *(const short8v*)(Vn + eb);
    short8v vb = *(const short8v*)(Vn + eb + 8);
    #pragma unroll
    for (int i = 0; i < 8; ++i) Vl[dh * 16 + i][k] = (unsigned short)va[i];
    #pragma unroll
    for (int i = 0; i < 8; ++i) Vl[dh * 16 + 8 + i][k] = (unsigned short)vb[i];
  }
  if (t < 256) {
    const float mv = mode ? maskg[(size_t)cr * NQ + t] : maskg[(size_t)t * NQ + cr];
    biasl[t] = (mv == 0.f) ? -1e30f : 0.f;
  }
  const int q0 = w * 32;
  short8v qf[2];
  #pragma unroll
  for (int qt = 0; qt < 2; ++qt) {
    const int q = q0 + qt * 16 + lr;
    const size_t eq = (mode ? ((size_t)cr * NQ + q) : ((size_t)q * NQ + cr)) * CF
                      + h * 32 + lg * 8;
    qf[qt] = *(const short8v*)(Qn + eq);
  }
  __syncthreads();

  f32x4 outv[2][2];
  #pragma unroll
  for (int qt = 0; qt < 2; ++qt)
    #pragma unroll
    for (int dt = 0; dt < 2; ++dt) outv[qt][dt] = (f32x4){0.f, 0.f, 0.f, 0.f};
  float psum[2][4] = {};

  #pragma unroll
  for (int kc = 0; kc < 8; ++kc) {
    #pragma unroll
    for (int kth = 0; kth < 2; ++kth) {
      const int kt = kc * 2 + kth;
      short8v kf = *(const short8v*)&Kl[kt * 16 + lr][lg * 8];
      const float bias = biasl[kt * 16 + lr];
      #pragma unroll
      for (int qt = 0; qt < 2; ++qt) {
        f32x4 z = {0.f, 0.f, 0.f, 0.f};
        f32x4 s = MFMA16(qf[qt], kf, z);
        #pragma unroll
        for (int r = 0; r < 4; ++r) {
          const float p = __expf(s[r] + bias);
          psum[qt][r] += p;
          Pb[w][qt * 16 + lg * 4 + r][kth * 16 + lr] = f2bf(p);
        }
      }
    }
    asm volatile("s_waitcnt lgkmcnt(0)" ::: "memory");
    short8v vf[2];
    #pragma unroll
    for (int dt = 0; dt < 2; ++dt)
      vf[dt] = *(const short8v*)&Vl[dt * 16 + lr][kc * 32 + lg * 8];
    #pragma unroll
    for (int qt = 0; qt < 2; ++qt) {
      short8v pf = *(const short8v*)&Pb[w][qt * 16 + lr][lg * 8];
      #pragma unroll
      for (int dt = 0; dt < 2; ++dt)
        outv[qt][dt] = MFMA16(pf, vf[dt], outv[qt][dt]);
    }
  }

  // normalize (0.5/rowsum), stash bf16 in Pb, coalesced store
  float inv[2][4];
  #pragma unroll
  for (int qt = 0; qt < 2; ++qt)
    #pragma unroll
    for (int r = 0; r < 4; ++r) {
      float ssum = psum[qt][r];
      ssum += __shfl_xor(ssum, 1);
      ssum += __shfl_xor(ssum, 2);
      ssum += __shfl_xor(ssum, 4);
      ssum += __shfl_xor(ssum, 8);
      inv[qt][r] = 0.5f / ssum;
    }
  #pragma unroll
  for (int qt = 0; qt < 2; ++qt)
    #pragma unroll
    for (int dt = 0; dt < 2; ++dt)
      #pragma unroll
      for (int r = 0; r < 4; ++r)
        Pb[w][qt * 16 + lg * 4 + r][dt * 16 + lr] = f2bf(outv[qt][dt][r] * inv[qt][r]);
  asm volatile("s_waitcnt lgkmcnt(0)" ::: "memory");
  short8v o0 = *(const short8v*)&Pb[w][l >> 1][(l & 1) * 16];
  short8v o1 = *(const short8v*)&Pb[w][l >> 1][(l & 1) * 16 + 8];
  asm volatile("s_waitcnt lgkmcnt(0)" ::: "memory");
  unsigned short* dst = mode ? att1 : att0;
  const int q = q0 + (l >> 1);
  const size_t edge = mode ? ((size_t)cr * NQ + q) : ((size_t)q * NQ + cr);
  const size_t ob = ((size_t)h * 65536 + edge) * 32 + (l & 1) * 16;
  *(short8v*)&dst[ob] = o0;
  *(short8v*)&dst[ob + 8] = o1;
}

// ---------------------------------------------------------------------------
// K3: MFMA out-proj + bias + residual + LayerNorm + mask -> d_out (f32).
// grid 1024, block 256 (4 waves). A = att0,att1 (bf16 head-major), summed
// via two MFMA chains. LN reduced in D-frag registers via shfl_xor.
// ---------------------------------------------------------------------------
extern "C" __global__ __launch_bounds__(256) void k_finalM(
    float* __restrict__ outb, const float* __restrict__ ef,
    const unsigned short* __restrict__ att0, const unsigned short* __restrict__ att1,
    const unsigned short* __restrict__ Wot, const float* __restrict__ bo,
    const float* __restrict__ gam, const float* __restrict__ bet,
    const float* __restrict__ maskg)
{
  const int t = threadIdx.x, w = t >> 6, l = t & 63;
  const int lr = l & 15, lg = l >> 4;
  const int e0 = blockIdx.x * 64 + w * 16;   // wave strip base

  short8v a0[4], a1[4];
  #pragma unroll
  for (int kg = 0; kg < 4; ++kg) {
    const size_t ab = ((size_t)kg * 65536 + e0 + lr) * 32 + lg * 8;
    a0[kg] = *(const short8v*)&att0[ab];
    a1[kg] = *(const short8v*)&att1[ab];
  }

  f32x4 acc[8];
  #pragma unroll
  for (int nt = 0; nt < 8; ++nt) acc[nt] = (f32x4){0.f, 0.f, 0.f, 0.f};
  #pragma unroll
  for (int nt = 0; nt < 8; ++nt) {
    const unsigned short* wrow = Wot + (size_t)(nt * 16 + lr) * 128;
    #pragma unroll
    for (int kg = 0; kg < 4; ++kg) {
      short8v bf = *(const short8v*)&wrow[kg * 32 + lg * 8];
      acc[nt] = MFMA16(a0[kg], bf, acc[nt]);
      acc[nt] = MFMA16(a1[kg], bf, acc[nt]);
    }
  }

  float bo_l[8], g_l[8], be_l[8];
  #pragma unroll
  for (int nt = 0; nt < 8; ++nt) {
    bo_l[nt] = bo[nt * 16 + lr];
    g_l[nt]  = gam[nt * 16 + lr];
    be_l[nt] = bet[nt * 16 + lr];
  }

  float s[4] = {}, s2[4] = {};
  #pragma unroll
  for (int nt = 0; nt < 8; ++nt)
    #pragma unroll
    for (int r = 0; r < 4; ++r) {
      const float res = ef[(size_t)(e0 + lg * 4 + r) * CF + nt * 16 + lr];
      const float v = acc[nt][r] + bo_l[nt] + res;
      acc[nt][r] = v;
      s[r] += v; s2[r] += v * v;
    }
  float mu[4], rstd[4], mk[4];
  #pragma unroll
  for (int r = 0; r < 4; ++r) {
    float a = s[r], b = s2[r];
    a += __shfl_xor(a, 1); b += __shfl_xor(b, 1);
    a += __shfl_xor(a, 2); b += __shfl_xor(b, 2);
    a += __shfl_xor(a, 4); b += __shfl_xor(b, 4);
    a += __shfl_xor(a, 8); b += __shfl_xor(b, 8);
    mu[r] = a * (1.f / 128.f);
    const float var = b * (1.f / 128.f) - mu[r] * mu[r];
    rstd[r] = rsqrtf(var + 1e-5f);
    mk[r] = maskg[e0 + lg * 4 + r];
  }
  #pragma unroll
  for (int nt = 0; nt < 8; ++nt)
    #pragma unroll
    for (int r = 0; r < 4; ++r) {
      const float yv = ((acc[nt][r] - mu[r]) * rstd[r] * g_l[nt] + be_l[nt]) * mk[r];
      outb[(size_t)(e0 + lg * 4 + r) * CF + nt * 16 + lr] = yv;
    }
}

// ---------------------------------------------------------------------------
extern "C" void kernel_launch(void* const* d_in, const int* in_sizes, int n_in,
                              void* d_out, int out_size, void* d_ws, size_t ws_size,
                              hipStream_t stream)
{
  (void)in_sizes; (void)n_in; (void)out_size; (void)ws_size;
  const float* ef   = (const float*)d_in[0];
  const float* mask = (const float*)d_in[1];
  const float* Wq   = (const float*)d_in[2];
  const float* Wk   = (const float*)d_in[3];
  const float* Wv   = (const float*)d_in[4];
  const float* Wo   = (const float*)d_in[5];
  const float* bo   = (const float*)d_in[6];
  const float* gam  = (const float*)d_in[7];
  const float* bet  = (const float*)d_in[8];
  float* out = (float*)d_out;
  const size_t BUF = (size_t)65536 * 128;       // 8M bf16 elems = 16MB
  unsigned short* Wt   = (unsigned short*)d_ws; // 4 x 16384 = 128KB
  unsigned short* Qn   = Wt + 4 * 16384;
  unsigned short* Kn   = Qn + BUF;
  unsigned short* Vn   = Kn + BUF;
  unsigned short* att0 = Vn + BUF;              // [4][65536][32] bf16 = 16MB
  unsigned short* att1 = att0 + BUF;            // total ~80.1MB

  k_cvt<<<dim3(4), dim3(256), 0, stream>>>(Wq, Wk, Wv, Wo, Wt);
  k_projM<<<dim3(2048), dim3(256), 0, stream>>>(ef, Wt, Qn, Kn, Vn);
  k_attn<<<dim3(256, 4, 2), dim3(512), 0, stream>>>(Qn, Kn, Vn, mask, att0, att1);
  k_finalM<<<dim3(1024), dim3(256), 0, stream>>>(out, ef, att0, att1,
                                                 Wt + 3 * 16384, bo, gam, bet, mask);
}

// Round 7
// 121.929 us; speedup vs baseline: 6.0558x; 1.1832x over previous
//
#include <hip/hip_runtime.h>
#include <math.h>

#define NQ 256      // D (grid side)
#define CF 128      // channels
#define RS 0.17677669529663687f  // 1/sqrt(32)

typedef __attribute__((ext_vector_type(8))) short short8v;   // 8 bf16 = 4 VGPR
typedef __attribute__((ext_vector_type(4))) float f32x4;

static __device__ __forceinline__ unsigned short f2bf(float x) {
  union { float f; unsigned u; } v; v.f = x;
  unsigned r = v.u + 0x7FFFu + ((v.u >> 16) & 1u);  // RNE
  return (unsigned short)(r >> 16);
}

static __device__ __forceinline__ short8v cvt8(float4 a, float4 b) {
  short8v r;
  r[0] = (short)f2bf(a.x); r[1] = (short)f2bf(a.y);
  r[2] = (short)f2bf(a.z); r[3] = (short)f2bf(a.w);
  r[4] = (short)f2bf(b.x); r[5] = (short)f2bf(b.y);
  r[6] = (short)f2bf(b.z); r[7] = (short)f2bf(b.w);
  return r;
}

#define MFMA16(a, b, c) __builtin_amdgcn_mfma_f32_16x16x32_bf16(a, b, c, 0, 0, 0)

// ---------------------------------------------------------------------------
// K0: weight prep. Wt[y][n][k] = bf16(W_y[k][n]), y in {q,k,v,o}. RS folded
// into Wq. grid 4 x 256.
// ---------------------------------------------------------------------------
extern "C" __global__ __launch_bounds__(256) void k_cvt(
    const float* __restrict__ Wq, const float* __restrict__ Wk,
    const float* __restrict__ Wv, const float* __restrict__ Wo,
    unsigned short* __restrict__ Wt)
{
  const int y = blockIdx.x;
  const float* W = (y == 0) ? Wq : (y == 1) ? Wk : (y == 2) ? Wv : Wo;
  unsigned short* dst = Wt + (size_t)y * 16384;
  const float sc = (y == 0) ? RS : 1.0f;
  const int t = threadIdx.x;
  #pragma unroll
  for (int i = 0; i < 16; ++i) {
    const int flat = (t + 256 * i) * 4;
    const int k = flat >> 7, n = flat & 127;
    float4 v = *(const float4*)&W[flat];
    dst[(n + 0) * 128 + k] = f2bf(v.x * sc);
    dst[(n + 1) * 128 + k] = f2bf(v.y * sc);
    dst[(n + 2) * 128 + k] = f2bf(v.z * sc);
    dst[(n + 3) * 128 + k] = f2bf(v.w * sc);
  }
}

// ---------------------------------------------------------------------------
// K1: MFMA projection -> edge-major bf16 Q/K/V. grid 1024, block 256
// (4 waves, no barriers, no LDS). Wave w owns N-quarter w*32 of all 3
// weights, B-frags register-resident (24 frags). Block processes 4 strips
// of 16 edges. Operand-swapped MFMA: D col=edge, row=channel -> each lane
// stores 4 consecutive channels (8B) directly, no stash.
// ---------------------------------------------------------------------------
extern "C" __global__ __launch_bounds__(256) void k_projM(
    const float* __restrict__ ef, const unsigned short* __restrict__ Wt,
    unsigned short* __restrict__ Qn, unsigned short* __restrict__ Kn,
    unsigned short* __restrict__ Vn)
{
  const int t = threadIdx.x, w = t >> 6, l = t & 63;
  const int lr = l & 15, lg = l >> 4;
  const int n0 = w * 32;

  // B preload: 3 weights x 2 nt x 4 kg, register-resident
  short8v bfrag[3][2][4];
  #pragma unroll
  for (int y = 0; y < 3; ++y)
    #pragma unroll
    for (int nt = 0; nt < 2; ++nt) {
      const unsigned short* wrow = Wt + (size_t)y * 16384
                                   + (size_t)(n0 + nt * 16 + lr) * 128;
      #pragma unroll
      for (int kg = 0; kg < 4; ++kg)
        bfrag[y][nt][kg] = *(const short8v*)&wrow[kg * 32 + lg * 8];
    }

  #pragma unroll
  for (int si = 0; si < 4; ++si) {
    const int es = (blockIdx.x * 4 + si) * 16;
    // A-frags (b-operand): ef row es+lr, k-offset lg*8
    short8v af[4];
    const float* arow = ef + (size_t)(es + lr) * CF;
    #pragma unroll
    for (int kg = 0; kg < 4; ++kg) {
      float4 a = *(const float4*)&arow[kg * 32 + lg * 8];
      float4 b = *(const float4*)&arow[kg * 32 + lg * 8 + 4];
      af[kg] = cvt8(a, b);
    }
    #pragma unroll
    for (int y = 0; y < 3; ++y) {
      unsigned short* Nb = (y == 0) ? Qn : (y == 1) ? Kn : Vn;
      #pragma unroll
      for (int nt = 0; nt < 2; ++nt) {
        f32x4 acc = {0.f, 0.f, 0.f, 0.f};
        #pragma unroll
        for (int kg = 0; kg < 4; ++kg)
          acc = MFMA16(bfrag[y][nt][kg], af[kg], acc);
        // D: col(lr)=edge, row(lg*4+r)=channel within this 16-block
        unsigned short pk[4];
        #pragma unroll
        for (int r = 0; r < 4; ++r) pk[r] = f2bf(acc[r]);
        const unsigned long long w64 =
            (unsigned long long)pk[0] | ((unsigned long long)pk[1] << 16) |
            ((unsigned long long)pk[2] << 32) | ((unsigned long long)pk[3] << 48);
        *(unsigned long long*)&Nb[(size_t)(es + lr) * CF + n0 + nt * 16 + lg * 4] = w64;
      }
    }
  }
}

// ---------------------------------------------------------------------------
// K2: MFMA attention, both modes in one launch. Block = (slice cr, head h,
// mode z). 8 waves x 32 q. Sources are edge-major Q/K/V: mode 0 gathers
// column-slice rows (L3-resident), mode 1 reads linear. No-max softmax
// (S ~ N(0,1); masked keys -> exp(-1e30) = 0). Output bf16 head-major
// att[h][edge][32], 0.5/rowsum folded.
// ---------------------------------------------------------------------------
extern "C" __global__ __launch_bounds__(512, 2) void k_attn(
    const unsigned short* __restrict__ Qn, const unsigned short* __restrict__ Kn,
    const unsigned short* __restrict__ Vn, const float* __restrict__ maskg,
    unsigned short* __restrict__ att0, unsigned short* __restrict__ att1)
{
  __shared__ unsigned short Kl[256][40];   // [k][d] pad 8
  __shared__ unsigned short Vl[32][264];   // [d][k] pad 8
  __shared__ float biasl[256];
  __shared__ unsigned short Pb[8][32][40]; // per-wave P chunk [q][k] pad 8
  const int cr = blockIdx.x, h = blockIdx.y, mode = blockIdx.z;
  const int t = threadIdx.x, w = t >> 6, l = t & 63;
  const int lr = l & 15, lg = l >> 4;

  {
    const int k = t >> 1, dh = t & 1;
    const size_t eb = (mode ? ((size_t)cr * NQ + k) : ((size_t)k * NQ + cr)) * CF
                      + h * 32 + dh * 16;
    short8v ka = *(const short8v*)(Kn + eb);
    short8v kb = *(const short8v*)(Kn + eb + 8);
    *(short8v*)&Kl[k][dh * 16] = ka;
    *(short8v*)&Kl[k][dh * 16 + 8] = kb;
    short8v va = *(const short8v*)(Vn + eb);
    short8v vb = *(const short8v*)(Vn + eb + 8);
    #pragma unroll
    for (int i = 0; i < 8; ++i) Vl[dh * 16 + i][k] = (unsigned short)va[i];
    #pragma unroll
    for (int i = 0; i < 8; ++i) Vl[dh * 16 + 8 + i][k] = (unsigned short)vb[i];
  }
  if (t < 256) {
    const float mv = mode ? maskg[(size_t)cr * NQ + t] : maskg[(size_t)t * NQ + cr];
    biasl[t] = (mv == 0.f) ? -1e30f : 0.f;
  }
  const int q0 = w * 32;
  short8v qf[2];
  #pragma unroll
  for (int qt = 0; qt < 2; ++qt) {
    const int q = q0 + qt * 16 + lr;
    const size_t eq = (mode ? ((size_t)cr * NQ + q) : ((size_t)q * NQ + cr)) * CF
                      + h * 32 + lg * 8;
    qf[qt] = *(const short8v*)(Qn + eq);
  }
  __syncthreads();

  f32x4 outv[2][2];
  #pragma unroll
  for (int qt = 0; qt < 2; ++qt)
    #pragma unroll
    for (int dt = 0; dt < 2; ++dt) outv[qt][dt] = (f32x4){0.f, 0.f, 0.f, 0.f};
  float psum[2][4] = {};

  #pragma unroll
  for (int kc = 0; kc < 8; ++kc) {
    #pragma unroll
    for (int kth = 0; kth < 2; ++kth) {
      const int kt = kc * 2 + kth;
      short8v kf = *(const short8v*)&Kl[kt * 16 + lr][lg * 8];
      const float bias = biasl[kt * 16 + lr];
      #pragma unroll
      for (int qt = 0; qt < 2; ++qt) {
        f32x4 z = {0.f, 0.f, 0.f, 0.f};
        f32x4 s = MFMA16(qf[qt], kf, z);
        #pragma unroll
        for (int r = 0; r < 4; ++r) {
          const float p = __expf(s[r] + bias);
          psum[qt][r] += p;
          Pb[w][qt * 16 + lg * 4 + r][kth * 16 + lr] = f2bf(p);
        }
      }
    }
    asm volatile("s_waitcnt lgkmcnt(0)" ::: "memory");
    short8v vf[2];
    #pragma unroll
    for (int dt = 0; dt < 2; ++dt)
      vf[dt] = *(const short8v*)&Vl[dt * 16 + lr][kc * 32 + lg * 8];
    #pragma unroll
    for (int qt = 0; qt < 2; ++qt) {
      short8v pf = *(const short8v*)&Pb[w][qt * 16 + lr][lg * 8];
      #pragma unroll
      for (int dt = 0; dt < 2; ++dt)
        outv[qt][dt] = MFMA16(pf, vf[dt], outv[qt][dt]);
    }
  }

  // normalize (0.5/rowsum), stash bf16 in Pb, coalesced store
  float inv[2][4];
  #pragma unroll
  for (int qt = 0; qt < 2; ++qt)
    #pragma unroll
    for (int r = 0; r < 4; ++r) {
      float ssum = psum[qt][r];
      ssum += __shfl_xor(ssum, 1);
      ssum += __shfl_xor(ssum, 2);
      ssum += __shfl_xor(ssum, 4);
      ssum += __shfl_xor(ssum, 8);
      inv[qt][r] = 0.5f / ssum;
    }
  #pragma unroll
  for (int qt = 0; qt < 2; ++qt)
    #pragma unroll
    for (int dt = 0; dt < 2; ++dt)
      #pragma unroll
      for (int r = 0; r < 4; ++r)
        Pb[w][qt * 16 + lg * 4 + r][dt * 16 + lr] = f2bf(outv[qt][dt][r] * inv[qt][r]);
  asm volatile("s_waitcnt lgkmcnt(0)" ::: "memory");
  short8v o0 = *(const short8v*)&Pb[w][l >> 1][(l & 1) * 16];
  short8v o1 = *(const short8v*)&Pb[w][l >> 1][(l & 1) * 16 + 8];
  asm volatile("s_waitcnt lgkmcnt(0)" ::: "memory");
  unsigned short* dst = mode ? att1 : att0;
  const int q = q0 + (l >> 1);
  const size_t edge = mode ? ((size_t)cr * NQ + q) : ((size_t)q * NQ + cr);
  const size_t ob = ((size_t)h * 65536 + edge) * 32 + (l & 1) * 16;
  *(short8v*)&dst[ob] = o0;
  *(short8v*)&dst[ob + 8] = o1;
}

// ---------------------------------------------------------------------------
// K3: MFMA out-proj + bias + residual + LayerNorm + mask -> d_out (f32).
// grid 1024, block 256 (4 waves). A = att0,att1 (bf16 head-major), summed
// via two MFMA chains. LN reduced in D-frag registers via shfl_xor.
// ---------------------------------------------------------------------------
extern "C" __global__ __launch_bounds__(256) void k_finalM(
    float* __restrict__ outb, const float* __restrict__ ef,
    const unsigned short* __restrict__ att0, const unsigned short* __restrict__ att1,
    const unsigned short* __restrict__ Wot, const float* __restrict__ bo,
    const float* __restrict__ gam, const float* __restrict__ bet,
    const float* __restrict__ maskg)
{
  const int t = threadIdx.x, w = t >> 6, l = t & 63;
  const int lr = l & 15, lg = l >> 4;
  const int e0 = blockIdx.x * 64 + w * 16;   // wave strip base

  short8v a0[4], a1[4];
  #pragma unroll
  for (int kg = 0; kg < 4; ++kg) {
    const size_t ab = ((size_t)kg * 65536 + e0 + lr) * 32 + lg * 8;
    a0[kg] = *(const short8v*)&att0[ab];
    a1[kg] = *(const short8v*)&att1[ab];
  }

  f32x4 acc[8];
  #pragma unroll
  for (int nt = 0; nt < 8; ++nt) acc[nt] = (f32x4){0.f, 0.f, 0.f, 0.f};
  #pragma unroll
  for (int nt = 0; nt < 8; ++nt) {
    const unsigned short* wrow = Wot + (size_t)(nt * 16 + lr) * 128;
    #pragma unroll
    for (int kg = 0; kg < 4; ++kg) {
      short8v bf = *(const short8v*)&wrow[kg * 32 + lg * 8];
      acc[nt] = MFMA16(a0[kg], bf, acc[nt]);
      acc[nt] = MFMA16(a1[kg], bf, acc[nt]);
    }
  }

  float bo_l[8], g_l[8], be_l[8];
  #pragma unroll
  for (int nt = 0; nt < 8; ++nt) {
    bo_l[nt] = bo[nt * 16 + lr];
    g_l[nt]  = gam[nt * 16 + lr];
    be_l[nt] = bet[nt * 16 + lr];
  }

  float s[4] = {}, s2[4] = {};
  #pragma unroll
  for (int nt = 0; nt < 8; ++nt)
    #pragma unroll
    for (int r = 0; r < 4; ++r) {
      const float res = ef[(size_t)(e0 + lg * 4 + r) * CF + nt * 16 + lr];
      const float v = acc[nt][r] + bo_l[nt] + res;
      acc[nt][r] = v;
      s[r] += v; s2[r] += v * v;
    }
  float mu[4], rstd[4], mk[4];
  #pragma unroll
  for (int r = 0; r < 4; ++r) {
    float a = s[r], b = s2[r];
    a += __shfl_xor(a, 1); b += __shfl_xor(b, 1);
    a += __shfl_xor(a, 2); b += __shfl_xor(b, 2);
    a += __shfl_xor(a, 4); b += __shfl_xor(b, 4);
    a += __shfl_xor(a, 8); b += __shfl_xor(b, 8);
    mu[r] = a * (1.f / 128.f);
    const float var = b * (1.f / 128.f) - mu[r] * mu[r];
    rstd[r] = rsqrtf(var + 1e-5f);
    mk[r] = maskg[e0 + lg * 4 + r];
  }
  #pragma unroll
  for (int nt = 0; nt < 8; ++nt)
    #pragma unroll
    for (int r = 0; r < 4; ++r) {
      const float yv = ((acc[nt][r] - mu[r]) * rstd[r] * g_l[nt] + be_l[nt]) * mk[r];
      outb[(size_t)(e0 + lg * 4 + r) * CF + nt * 16 + lr] = yv;
    }
}

// ---------------------------------------------------------------------------
extern "C" void kernel_launch(void* const* d_in, const int* in_sizes, int n_in,
                              void* d_out, int out_size, void* d_ws, size_t ws_size,
                              hipStream_t stream)
{
  (void)in_sizes; (void)n_in; (void)out_size; (void)ws_size;
  const float* ef   = (const float*)d_in[0];
  const float* mask = (const float*)d_in[1];
  const float* Wq   = (const float*)d_in[2];
  const float* Wk   = (const float*)d_in[3];
  const float* Wv   = (const float*)d_in[4];
  const float* Wo   = (const float*)d_in[5];
  const float* bo   = (const float*)d_in[6];
  const float* gam  = (const float*)d_in[7];
  const float* bet  = (const float*)d_in[8];
  float* out = (float*)d_out;
  const size_t BUF = (size_t)65536 * 128;       // 8M bf16 elems = 16MB
  unsigned short* Wt   = (unsigned short*)d_ws; // 4 x 16384 = 128KB
  unsigned short* Qn   = Wt + 4 * 16384;
  unsigned short* Kn   = Qn + BUF;
  unsigned short* Vn   = Kn + BUF;
  unsigned short* att0 = Vn + BUF;              // [4][65536][32] bf16 = 16MB
  unsigned short* att1 = att0 + BUF;            // total ~80.1MB

  k_cvt<<<dim3(4), dim3(256), 0, stream>>>(Wq, Wk, Wv, Wo, Wt);
  k_projM<<<dim3(1024), dim3(256), 0, stream>>>(ef, Wt, Qn, Kn, Vn);
  k_attn<<<dim3(256, 4, 2), dim3(512), 0, stream>>>(Qn, Kn, Vn, mask, att0, att1);
  k_finalM<<<dim3(1024), dim3(256), 0, stream>>>(out, ef, att0, att1,
                                                 Wt + 3 * 16384, bo, gam, bet, mask);
}

// Round 9
// 121.324 us; speedup vs baseline: 6.0860x; 1.0050x over previous
//
#include <hip/hip_runtime.h>
#include <hip/hip_bf16.h>
#include <math.h>

#define NQ 256      // D (grid side)
#define CF 128      // channels
#define RS 0.17677669529663687f  // 1/sqrt(32)

typedef __attribute__((ext_vector_type(8))) short short8v;   // 8 bf16 = 4 VGPR
typedef __attribute__((ext_vector_type(4))) float f32x4;

static __device__ __forceinline__ unsigned short f2bf(float x) {
  union { float f; unsigned u; } v; v.f = x;
  unsigned r = v.u + 0x7FFFu + ((v.u >> 16) & 1u);  // RNE
  return (unsigned short)(r >> 16);
}

// packed f32x2 -> bf16x2 (compiler emits v_cvt_pk_bf16_f32)
static __device__ __forceinline__ unsigned pack2(float a, float b) {
  __hip_bfloat162 h = __float22bfloat162_rn(make_float2(a, b));
  union { __hip_bfloat162 h; unsigned u; } c; c.h = h; return c.u;
}
static __device__ __forceinline__ unsigned long long pack4(float a, float b,
                                                           float c, float d) {
  return (unsigned long long)pack2(a, b) | ((unsigned long long)pack2(c, d) << 32);
}
static __device__ __forceinline__ short8v cvt8(float4 a, float4 b) {
  union { short8v s; unsigned u[4]; } r;
  r.u[0] = pack2(a.x, a.y); r.u[1] = pack2(a.z, a.w);
  r.u[2] = pack2(b.x, b.y); r.u[3] = pack2(b.z, b.w);
  return r.s;
}

#define MFMA16(a, b, c) __builtin_amdgcn_mfma_f32_16x16x32_bf16(a, b, c, 0, 0, 0)

// ---------------------------------------------------------------------------
// K0: weight prep. Wt[y][n][k] = bf16(W_y[k][n]), y in {q,k,v,o}. RS folded
// into Wq. grid 4 x 256.
// ---------------------------------------------------------------------------
extern "C" __global__ __launch_bounds__(256) void k_cvt(
    const float* __restrict__ Wq, const float* __restrict__ Wk,
    const float* __restrict__ Wv, const float* __restrict__ Wo,
    unsigned short* __restrict__ Wt)
{
  const int y = blockIdx.x;
  const float* W = (y == 0) ? Wq : (y == 1) ? Wk : (y == 2) ? Wv : Wo;
  unsigned short* dst = Wt + (size_t)y * 16384;
  const float sc = (y == 0) ? RS : 1.0f;
  const int t = threadIdx.x;
  #pragma unroll
  for (int i = 0; i < 16; ++i) {
    const int flat = (t + 256 * i) * 4;
    const int k = flat >> 7, n = flat & 127;
    float4 v = *(const float4*)&W[flat];
    dst[(n + 0) * 128 + k] = f2bf(v.x * sc);
    dst[(n + 1) * 128 + k] = f2bf(v.y * sc);
    dst[(n + 2) * 128 + k] = f2bf(v.z * sc);
    dst[(n + 3) * 128 + k] = f2bf(v.w * sc);
  }
}

// ---------------------------------------------------------------------------
// K1: MFMA projection -> edge-major bf16 Q/K/V. grid 1024, block 256
// (4 waves, no barriers, no LDS). Wave w owns N-quarter w*32 of all 3
// weights, B-frags register-resident. Operand-swapped MFMA: D col=edge,
// row=channel -> each lane stores 4 consecutive channels (8B) directly.
// ---------------------------------------------------------------------------
extern "C" __global__ __launch_bounds__(256) void k_projM(
    const float* __restrict__ ef, const unsigned short* __restrict__ Wt,
    unsigned short* __restrict__ Qn, unsigned short* __restrict__ Kn,
    unsigned short* __restrict__ Vn)
{
  const int t = threadIdx.x, w = t >> 6, l = t & 63;
  const int lr = l & 15, lg = l >> 4;
  const int n0 = w * 32;

  short8v bfrag[3][2][4];
  #pragma unroll
  for (int y = 0; y < 3; ++y)
    #pragma unroll
    for (int nt = 0; nt < 2; ++nt) {
      const unsigned short* wrow = Wt + (size_t)y * 16384
                                   + (size_t)(n0 + nt * 16 + lr) * 128;
      #pragma unroll
      for (int kg = 0; kg < 4; ++kg)
        bfrag[y][nt][kg] = *(const short8v*)&wrow[kg * 32 + lg * 8];
    }

  #pragma unroll
  for (int si = 0; si < 4; ++si) {
    const int es = (blockIdx.x * 4 + si) * 16;
    short8v af[4];
    const float* arow = ef + (size_t)(es + lr) * CF;
    #pragma unroll
    for (int kg = 0; kg < 4; ++kg) {
      float4 a = *(const float4*)&arow[kg * 32 + lg * 8];
      float4 b = *(const float4*)&arow[kg * 32 + lg * 8 + 4];
      af[kg] = cvt8(a, b);
    }
    #pragma unroll
    for (int y = 0; y < 3; ++y) {
      unsigned short* Nb = (y == 0) ? Qn : (y == 1) ? Kn : Vn;
      #pragma unroll
      for (int nt = 0; nt < 2; ++nt) {
        f32x4 acc = {0.f, 0.f, 0.f, 0.f};
        #pragma unroll
        for (int kg = 0; kg < 4; ++kg)
          acc = MFMA16(bfrag[y][nt][kg], af[kg], acc);
        *(unsigned long long*)&Nb[(size_t)(es + lr) * CF + n0 + nt * 16 + lg * 4] =
            pack4(acc[0], acc[1], acc[2], acc[3]);
      }
    }
  }
}

// ---------------------------------------------------------------------------
// K2: MFMA attention, operand-swapped. Block = (slice cr, head h, mode z),
// 8 waves x 32 q. Swapped QK^T: D col=q, row=k -> lane holds 4 consecutive
// k for one q -> packed 8B P-writes. Multiplicative mask (m in {0,1}).
// Swapped PV: D col=q, row=d -> packed 8B out-stash. No-max softmax.
// Output bf16 head-major att[h][edge][32], 0.5/rowsum folded.
// ---------------------------------------------------------------------------
extern "C" __global__ __launch_bounds__(512, 2) void k_attn(
    const unsigned short* __restrict__ Qn, const unsigned short* __restrict__ Kn,
    const unsigned short* __restrict__ Vn, const float* __restrict__ maskg,
    unsigned short* __restrict__ att0, unsigned short* __restrict__ att1)
{
  __shared__ unsigned short Kl[256][40];   // [k][d] pad 8
  __shared__ unsigned short Vl[32][264];   // [d][k] pad 8
  __shared__ float maskl[256];
  __shared__ unsigned short Pb[8][32][40]; // per-wave P chunk [q][k] pad 8
  const int cr = blockIdx.x, h = blockIdx.y, mode = blockIdx.z;
  const int t = threadIdx.x, w = t >> 6, l = t & 63;
  const int lr = l & 15, lg = l >> 4;

  {
    const int k = t >> 1, dh = t & 1;
    const size_t eb = (mode ? ((size_t)cr * NQ + k) : ((size_t)k * NQ + cr)) * CF
                      + h * 32 + dh * 16;
    short8v ka = *(const short8v*)(Kn + eb);
    short8v kb = *(const short8v*)(Kn + eb + 8);
    *(short8v*)&Kl[k][dh * 16] = ka;
    *(short8v*)&Kl[k][dh * 16 + 8] = kb;
    short8v va = *(const short8v*)(Vn + eb);
    short8v vb = *(const short8v*)(Vn + eb + 8);
    #pragma unroll
    for (int i = 0; i < 8; ++i) Vl[dh * 16 + i][k] = (unsigned short)va[i];
    #pragma unroll
    for (int i = 0; i < 8; ++i) Vl[dh * 16 + 8 + i][k] = (unsigned short)vb[i];
  }
  if (t < 256)
    maskl[t] = mode ? maskg[(size_t)cr * NQ + t] : maskg[(size_t)t * NQ + cr];

  const int q0 = w * 32;
  short8v qf[2];
  #pragma unroll
  for (int qt = 0; qt < 2; ++qt) {
    const int q = q0 + qt * 16 + lr;
    const size_t eq = (mode ? ((size_t)cr * NQ + q) : ((size_t)q * NQ + cr)) * CF
                      + h * 32 + lg * 8;
    qf[qt] = *(const short8v*)(Qn + eq);
  }
  __syncthreads();

  f32x4 outv[2][2];   // [qt][dt]: D col=q(lr), row=d(lg*4+r)
  #pragma unroll
  for (int qt = 0; qt < 2; ++qt)
    #pragma unroll
    for (int dt = 0; dt < 2; ++dt) outv[qt][dt] = (f32x4){0.f, 0.f, 0.f, 0.f};
  float psum[2] = {0.f, 0.f};

  #pragma unroll
  for (int kc = 0; kc < 8; ++kc) {
    #pragma unroll
    for (int kth = 0; kth < 2; ++kth) {
      const int kt = kc * 2 + kth;
      short8v kf = *(const short8v*)&Kl[kt * 16 + lr][lg * 8];
      float4 mv4 = *(const float4*)&maskl[kt * 16 + lg * 4];
      #pragma unroll
      for (int qt = 0; qt < 2; ++qt) {
        f32x4 z = {0.f, 0.f, 0.f, 0.f};
        f32x4 s = MFMA16(kf, qf[qt], z);   // swapped: col=q, row=k
        const float p0 = mv4.x * __expf(s[0]);
        const float p1 = mv4.y * __expf(s[1]);
        const float p2 = mv4.z * __expf(s[2]);
        const float p3 = mv4.w * __expf(s[3]);
        psum[qt] += (p0 + p1) + (p2 + p3);
        *(unsigned long long*)&Pb[w][qt * 16 + lr][kth * 16 + lg * 4] =
            pack4(p0, p1, p2, p3);
      }
    }
    asm volatile("s_waitcnt lgkmcnt(0)" ::: "memory");
    short8v vf[2];
    #pragma unroll
    for (int dt = 0; dt < 2; ++dt)
      vf[dt] = *(const short8v*)&Vl[dt * 16 + lr][kc * 32 + lg * 8];
    #pragma unroll
    for (int qt = 0; qt < 2; ++qt) {
      short8v pf = *(const short8v*)&Pb[w][qt * 16 + lr][lg * 8];
      #pragma unroll
      for (int dt = 0; dt < 2; ++dt)
        outv[qt][dt] = MFMA16(vf[dt], pf, outv[qt][dt]);  // swapped: col=q, row=d
    }
  }

  // rowsum: lane-scalar, reduce across the 4 lg-groups (lane bits 4,5)
  float inv[2];
  #pragma unroll
  for (int qt = 0; qt < 2; ++qt) {
    float ssum = psum[qt];
    ssum += __shfl_xor(ssum, 16);
    ssum += __shfl_xor(ssum, 32);
    inv[qt] = 0.5f / ssum;
  }
  #pragma unroll
  for (int qt = 0; qt < 2; ++qt)
    #pragma unroll
    for (int dt = 0; dt < 2; ++dt)
      *(unsigned long long*)&Pb[w][qt * 16 + lr][dt * 16 + lg * 4] =
          pack4(outv[qt][dt][0] * inv[qt], outv[qt][dt][1] * inv[qt],
                outv[qt][dt][2] * inv[qt], outv[qt][dt][3] * inv[qt]);
  asm volatile("s_waitcnt lgkmcnt(0)" ::: "memory");
  short8v o0 = *(const short8v*)&Pb[w][l >> 1][(l & 1) * 16];
  short8v o1 = *(const short8v*)&Pb[w][l >> 1][(l & 1) * 16 + 8];
  asm volatile("s_waitcnt lgkmcnt(0)" ::: "memory");
  unsigned short* dst = mode ? att1 : att0;
  const int q = q0 + (l >> 1);
  const size_t edge = mode ? ((size_t)cr * NQ + q) : ((size_t)q * NQ + cr);
  const size_t ob = ((size_t)h * 65536 + edge) * 32 + (l & 1) * 16;
  *(short8v*)&dst[ob] = o0;
  *(short8v*)&dst[ob + 8] = o1;
}

// ---------------------------------------------------------------------------
// K3: MFMA out-proj + bias + residual + LayerNorm + mask -> d_out (f32).
// grid 1024, block 256 (4 waves). A = att0,att1 (bf16 head-major), summed
// via two MFMA chains. LN reduced in D-frag registers via shfl_xor.
// ---------------------------------------------------------------------------
extern "C" __global__ __launch_bounds__(256) void k_finalM(
    float* __restrict__ outb, const float* __restrict__ ef,
    const unsigned short* __restrict__ att0, const unsigned short* __restrict__ att1,
    const unsigned short* __restrict__ Wot, const float* __restrict__ bo,
    const float* __restrict__ gam, const float* __restrict__ bet,
    const float* __restrict__ maskg)
{
  const int t = threadIdx.x, w = t >> 6, l = t & 63;
  const int lr = l & 15, lg = l >> 4;
  const int e0 = blockIdx.x * 64 + w * 16;   // wave strip base

  short8v a0[4], a1[4];
  #pragma unroll
  for (int kg = 0; kg < 4; ++kg) {
    const size_t ab = ((size_t)kg * 65536 + e0 + lr) * 32 + lg * 8;
    a0[kg] = *(const short8v*)&att0[ab];
    a1[kg] = *(const short8v*)&att1[ab];
  }

  f32x4 acc[8];
  #pragma unroll
  for (int nt = 0; nt < 8; ++nt) acc[nt] = (f32x4){0.f, 0.f, 0.f, 0.f};
  #pragma unroll
  for (int nt = 0; nt < 8; ++nt) {
    const unsigned short* wrow = Wot + (size_t)(nt * 16 + lr) * 128;
    #pragma unroll
    for (int kg = 0; kg < 4; ++kg) {
      short8v bf = *(const short8v*)&wrow[kg * 32 + lg * 8];
      acc[nt] = MFMA16(a0[kg], bf, acc[nt]);
      acc[nt] = MFMA16(a1[kg], bf, acc[nt]);
    }
  }

  float bo_l[8], g_l[8], be_l[8];
  #pragma unroll
  for (int nt = 0; nt < 8; ++nt) {
    bo_l[nt] = bo[nt * 16 + lr];
    g_l[nt]  = gam[nt * 16 + lr];
    be_l[nt] = bet[nt * 16 + lr];
  }

  float s[4] = {}, s2[4] = {};
  #pragma unroll
  for (int nt = 0; nt < 8; ++nt)
    #pragma unroll
    for (int r = 0; r < 4; ++r) {
      const float res = ef[(size_t)(e0 + lg * 4 + r) * CF + nt * 16 + lr];
      const float v = acc[nt][r] + bo_l[nt] + res;
      acc[nt][r] = v;
      s[r] += v; s2[r] += v * v;
    }
  float mu[4], rstd[4], mk[4];
  #pragma unroll
  for (int r = 0; r < 4; ++r) {
    float a = s[r], b = s2[r];
    a += __shfl_xor(a, 1); b += __shfl_xor(b, 1);
    a += __shfl_xor(a, 2); b += __shfl_xor(b, 2);
    a += __shfl_xor(a, 4); b += __shfl_xor(b, 4);
    a += __shfl_xor(a, 8); b += __shfl_xor(b, 8);
    mu[r] = a * (1.f / 128.f);
    const float var = b * (1.f / 128.f) - mu[r] * mu[r];
    rstd[r] = rsqrtf(var + 1e-5f);
    mk[r] = maskg[e0 + lg * 4 + r];
  }
  #pragma unroll
  for (int nt = 0; nt < 8; ++nt)
    #pragma unroll
    for (int r = 0; r < 4; ++r) {
      const float yv = ((acc[nt][r] - mu[r]) * rstd[r] * g_l[nt] + be_l[nt]) * mk[r];
      outb[(size_t)(e0 + lg * 4 + r) * CF + nt * 16 + lr] = yv;
    }
}

// ---------------------------------------------------------------------------
extern "C" void kernel_launch(void* const* d_in, const int* in_sizes, int n_in,
                              void* d_out, int out_size, void* d_ws, size_t ws_size,
                              hipStream_t stream)
{
  (void)in_sizes; (void)n_in; (void)out_size; (void)ws_size;
  const float* ef   = (const float*)d_in[0];
  const float* mask = (const float*)d_in[1];
  const float* Wq   = (const float*)d_in[2];
  const float* Wk   = (const float*)d_in[3];
  const float* Wv   = (const float*)d_in[4];
  const float* Wo   = (const float*)d_in[5];
  const float* bo   = (const float*)d_in[6];
  const float* gam  = (const float*)d_in[7];
  const float* bet  = (const float*)d_in[8];
  float* out = (float*)d_out;
  const size_t BUF = (size_t)65536 * 128;       // 8M bf16 elems = 16MB
  unsigned short* Wt   = (unsigned short*)d_ws; // 4 x 16384 = 128KB
  unsigned short* Qn   = Wt + 4 * 16384;
  unsigned short* Kn   = Qn + BUF;
  unsigned short* Vn   = Kn + BUF;
  unsigned short* att0 = Vn + BUF;              // [4][65536][32] bf16 = 16MB
  unsigned short* att1 = att0 + BUF;            // total ~80.1MB

  k_cvt<<<dim3(4), dim3(256), 0, stream>>>(Wq, Wk, Wv, Wo, Wt);
  k_projM<<<dim3(1024), dim3(256), 0, stream>>>(ef, Wt, Qn, Kn, Vn);
  k_attn<<<dim3(256, 4, 2), dim3(512), 0, stream>>>(Qn, Kn, Vn, mask, att0, att1);
  k_finalM<<<dim3(1024), dim3(256), 0, stream>>>(out, ef, att0, att1,
                                                 Wt + 3 * 16384, bo, gam, bet, mask);
}

// Round 11
// 117.699 us; speedup vs baseline: 6.2734x; 1.0308x over previous
//
#include <hip/hip_runtime.h>
#include <hip/hip_bf16.h>
#include <math.h>

#define NQ 256      // D (grid side)
#define CF 128      // channels
#define RS 0.17677669529663687f   // 1/sqrt(32)
#define RSL2E 0.2550565392829014f // RS * log2(e): QK^T in log2 domain

typedef __attribute__((ext_vector_type(8))) short short8v;   // 8 bf16 = 4 VGPR
typedef __attribute__((ext_vector_type(4))) float f32x4;

static __device__ __forceinline__ unsigned short f2bf(float x) {
  union { float f; unsigned u; } v; v.f = x;
  unsigned r = v.u + 0x7FFFu + ((v.u >> 16) & 1u);  // RNE
  return (unsigned short)(r >> 16);
}

// packed f32x2 -> bf16x2 (compiler emits v_cvt_pk_bf16_f32, hazards handled)
static __device__ __forceinline__ unsigned pack2(float a, float b) {
  __hip_bfloat162 h = __float22bfloat162_rn(make_float2(a, b));
  union { __hip_bfloat162 h; unsigned u; } c; c.h = h; return c.u;
}
static __device__ __forceinline__ unsigned long long pack4(float a, float b,
                                                           float c, float d) {
  return (unsigned long long)pack2(a, b) | ((unsigned long long)pack2(c, d) << 32);
}
static __device__ __forceinline__ short8v cvt8(float4 a, float4 b) {
  union { short8v s; unsigned u[4]; } r;
  r.u[0] = pack2(a.x, a.y); r.u[1] = pack2(a.z, a.w);
  r.u[2] = pack2(b.x, b.y); r.u[3] = pack2(b.z, b.w);
  return r.s;
}
// single v_exp_f32 via compiler intrinsic (hazards handled)
#if __has_builtin(__builtin_amdgcn_exp2f)
#define EXP2F(x) __builtin_amdgcn_exp2f(x)
#else
#define EXP2F(x) exp2f(x)
#endif

#define MFMA16(a, b, c) __builtin_amdgcn_mfma_f32_16x16x32_bf16(a, b, c, 0, 0, 0)

// ---------------------------------------------------------------------------
// K0: weight prep. Wt[y][n][k] = bf16(W_y[k][n]), y in {q,k,v,o}. RS*log2e
// folded into Wq (attention softmax runs in base-2). grid 4 x 256.
// ---------------------------------------------------------------------------
extern "C" __global__ __launch_bounds__(256) void k_cvt(
    const float* __restrict__ Wq, const float* __restrict__ Wk,
    const float* __restrict__ Wv, const float* __restrict__ Wo,
    unsigned short* __restrict__ Wt)
{
  const int y = blockIdx.x;
  const float* W = (y == 0) ? Wq : (y == 1) ? Wk : (y == 2) ? Wv : Wo;
  unsigned short* dst = Wt + (size_t)y * 16384;
  const float sc = (y == 0) ? RSL2E : 1.0f;
  const int t = threadIdx.x;
  #pragma unroll
  for (int i = 0; i < 16; ++i) {
    const int flat = (t + 256 * i) * 4;
    const int k = flat >> 7, n = flat & 127;
    float4 v = *(const float4*)&W[flat];
    dst[(n + 0) * 128 + k] = f2bf(v.x * sc);
    dst[(n + 1) * 128 + k] = f2bf(v.y * sc);
    dst[(n + 2) * 128 + k] = f2bf(v.z * sc);
    dst[(n + 3) * 128 + k] = f2bf(v.w * sc);
  }
}

// ---------------------------------------------------------------------------
// K1: MFMA projection -> edge-major bf16 Q/K/V. grid 1024, block 256
// (4 waves, no barriers, no LDS). __launch_bounds__(256,2): <=256 VGPR so
// the 24 B-frags (96 VGPR) stay register-resident (r9: VGPR=80 forced
// spills -> latency-bound at 59us). Operand-swapped MFMA: D col=edge,
// row=channel -> each lane stores 4 consecutive channels (8B) directly.
// ---------------------------------------------------------------------------
extern "C" __global__ __launch_bounds__(256, 2) void k_projM(
    const float* __restrict__ ef, const unsigned short* __restrict__ Wt,
    unsigned short* __restrict__ Qn, unsigned short* __restrict__ Kn,
    unsigned short* __restrict__ Vn)
{
  const int t = threadIdx.x, w = t >> 6, l = t & 63;
  const int lr = l & 15, lg = l >> 4;
  const int n0 = w * 32;

  short8v bfrag[3][2][4];
  #pragma unroll
  for (int y = 0; y < 3; ++y)
    #pragma unroll
    for (int nt = 0; nt < 2; ++nt) {
      const unsigned short* wrow = Wt + (size_t)y * 16384
                                   + (size_t)(n0 + nt * 16 + lr) * 128;
      #pragma unroll
      for (int kg = 0; kg < 4; ++kg)
        bfrag[y][nt][kg] = *(const short8v*)&wrow[kg * 32 + lg * 8];
    }

  #pragma unroll
  for (int si = 0; si < 4; ++si) {
    const int es = (blockIdx.x * 4 + si) * 16;
    short8v af[4];
    const float* arow = ef + (size_t)(es + lr) * CF;
    #pragma unroll
    for (int kg = 0; kg < 4; ++kg) {
      float4 a = *(const float4*)&arow[kg * 32 + lg * 8];
      float4 b = *(const float4*)&arow[kg * 32 + lg * 8 + 4];
      af[kg] = cvt8(a, b);
    }
    #pragma unroll
    for (int y = 0; y < 3; ++y) {
      unsigned short* Nb = (y == 0) ? Qn : (y == 1) ? Kn : Vn;
      #pragma unroll
      for (int nt = 0; nt < 2; ++nt) {
        f32x4 acc = {0.f, 0.f, 0.f, 0.f};
        #pragma unroll
        for (int kg = 0; kg < 4; ++kg)
          acc = MFMA16(bfrag[y][nt][kg], af[kg], acc);
        *(unsigned long long*)&Nb[(size_t)(es + lr) * CF + n0 + nt * 16 + lg * 4] =
            pack4(acc[0], acc[1], acc[2], acc[3]);
      }
    }
  }
}

// ---------------------------------------------------------------------------
// K2: MFMA attention, operand-swapped, base-2 softmax. Block = (slice cr,
// head h, mode z), 8 waves x 32 q. Swapped QK^T: D col=q, row=k -> packed
// 8B P-writes. Multiplicative mask. Swapped PV: D col=q, row=d.
// Output bf16 head-major att[h][edge][32], 0.5/rowsum folded.
// ---------------------------------------------------------------------------
extern "C" __global__ __launch_bounds__(512, 2) void k_attn(
    const unsigned short* __restrict__ Qn, const unsigned short* __restrict__ Kn,
    const unsigned short* __restrict__ Vn, const float* __restrict__ maskg,
    unsigned short* __restrict__ att0, unsigned short* __restrict__ att1)
{
  __shared__ unsigned short Kl[256][40];   // [k][d] pad 8
  __shared__ unsigned short Vl[32][264];   // [d][k] pad 8
  __shared__ float maskl[256];
  __shared__ unsigned short Pb[8][32][40]; // per-wave P chunk [q][k] pad 8
  const int cr = blockIdx.x, h = blockIdx.y, mode = blockIdx.z;
  const int t = threadIdx.x, w = t >> 6, l = t & 63;
  const int lr = l & 15, lg = l >> 4;

  {
    const int k = t >> 1, dh = t & 1;
    const size_t eb = (mode ? ((size_t)cr * NQ + k) : ((size_t)k * NQ + cr)) * CF
                      + h * 32 + dh * 16;
    short8v ka = *(const short8v*)(Kn + eb);
    short8v kb = *(const short8v*)(Kn + eb + 8);
    *(short8v*)&Kl[k][dh * 16] = ka;
    *(short8v*)&Kl[k][dh * 16 + 8] = kb;
    short8v va = *(const short8v*)(Vn + eb);
    short8v vb = *(const short8v*)(Vn + eb + 8);
    #pragma unroll
    for (int i = 0; i < 8; ++i) Vl[dh * 16 + i][k] = (unsigned short)va[i];
    #pragma unroll
    for (int i = 0; i < 8; ++i) Vl[dh * 16 + 8 + i][k] = (unsigned short)vb[i];
  }
  if (t < 256)
    maskl[t] = mode ? maskg[(size_t)cr * NQ + t] : maskg[(size_t)t * NQ + cr];

  const int q0 = w * 32;
  short8v qf[2];
  #pragma unroll
  for (int qt = 0; qt < 2; ++qt) {
    const int q = q0 + qt * 16 + lr;
    const size_t eq = (mode ? ((size_t)cr * NQ + q) : ((size_t)q * NQ + cr)) * CF
                      + h * 32 + lg * 8;
    qf[qt] = *(const short8v*)(Qn + eq);
  }
  __syncthreads();

  f32x4 outv[2][2];   // [qt][dt]: D col=q(lr), row=d(lg*4+r)
  #pragma unroll
  for (int qt = 0; qt < 2; ++qt)
    #pragma unroll
    for (int dt = 0; dt < 2; ++dt) outv[qt][dt] = (f32x4){0.f, 0.f, 0.f, 0.f};
  float psum[2] = {0.f, 0.f};

  #pragma unroll
  for (int kc = 0; kc < 8; ++kc) {
    #pragma unroll
    for (int kth = 0; kth < 2; ++kth) {
      const int kt = kc * 2 + kth;
      short8v kf = *(const short8v*)&Kl[kt * 16 + lr][lg * 8];
      float4 mv4 = *(const float4*)&maskl[kt * 16 + lg * 4];
      #pragma unroll
      for (int qt = 0; qt < 2; ++qt) {
        f32x4 z = {0.f, 0.f, 0.f, 0.f};
        f32x4 s = MFMA16(kf, qf[qt], z);   // swapped: col=q, row=k (log2 domain)
        const float p0 = mv4.x * EXP2F(s[0]);
        const float p1 = mv4.y * EXP2F(s[1]);
        const float p2 = mv4.z * EXP2F(s[2]);
        const float p3 = mv4.w * EXP2F(s[3]);
        psum[qt] += (p0 + p1) + (p2 + p3);
        *(unsigned long long*)&Pb[w][qt * 16 + lr][kth * 16 + lg * 4] =
            pack4(p0, p1, p2, p3);
      }
    }
    asm volatile("s_waitcnt lgkmcnt(0)" ::: "memory");
    short8v vf[2];
    #pragma unroll
    for (int dt = 0; dt < 2; ++dt)
      vf[dt] = *(const short8v*)&Vl[dt * 16 + lr][kc * 32 + lg * 8];
    #pragma unroll
    for (int qt = 0; qt < 2; ++qt) {
      short8v pf = *(const short8v*)&Pb[w][qt * 16 + lr][lg * 8];
      #pragma unroll
      for (int dt = 0; dt < 2; ++dt)
        outv[qt][dt] = MFMA16(vf[dt], pf, outv[qt][dt]);  // swapped: col=q, row=d
    }
  }

  // rowsum: lane-scalar, reduce across the 4 lg-groups (lane bits 4,5)
  float inv[2];
  #pragma unroll
  for (int qt = 0; qt < 2; ++qt) {
    float ssum = psum[qt];
    ssum += __shfl_xor(ssum, 16);
    ssum += __shfl_xor(ssum, 32);
    inv[qt] = 0.5f / ssum;
  }
  #pragma unroll
  for (int qt = 0; qt < 2; ++qt)
    #pragma unroll
    for (int dt = 0; dt < 2; ++dt)
      *(unsigned long long*)&Pb[w][qt * 16 + lr][dt * 16 + lg * 4] =
          pack4(outv[qt][dt][0] * inv[qt], outv[qt][dt][1] * inv[qt],
                outv[qt][dt][2] * inv[qt], outv[qt][dt][3] * inv[qt]);
  asm volatile("s_waitcnt lgkmcnt(0)" ::: "memory");
  short8v o0 = *(const short8v*)&Pb[w][l >> 1][(l & 1) * 16];
  short8v o1 = *(const short8v*)&Pb[w][l >> 1][(l & 1) * 16 + 8];
  asm volatile("s_waitcnt lgkmcnt(0)" ::: "memory");
  unsigned short* dst = mode ? att1 : att0;
  const int q = q0 + (l >> 1);
  const size_t edge = mode ? ((size_t)cr * NQ + q) : ((size_t)q * NQ + cr);
  const size_t ob = ((size_t)h * 65536 + edge) * 32 + (l & 1) * 16;
  *(short8v*)&dst[ob] = o0;
  *(short8v*)&dst[ob + 8] = o1;
}

// ---------------------------------------------------------------------------
// K3: MFMA out-proj + bias + residual + LayerNorm + mask -> d_out (f32).
// grid 1024, block 256 (4 waves). A = att0,att1 (bf16 head-major), summed
// via two MFMA chains. LN reduced in D-frag registers via shfl_xor.
// ---------------------------------------------------------------------------
extern "C" __global__ __launch_bounds__(256) void k_finalM(
    float* __restrict__ outb, const float* __restrict__ ef,
    const unsigned short* __restrict__ att0, const unsigned short* __restrict__ att1,
    const unsigned short* __restrict__ Wot, const float* __restrict__ bo,
    const float* __restrict__ gam, const float* __restrict__ bet,
    const float* __restrict__ maskg)
{
  const int t = threadIdx.x, w = t >> 6, l = t & 63;
  const int lr = l & 15, lg = l >> 4;
  const int e0 = blockIdx.x * 64 + w * 16;   // wave strip base

  short8v a0[4], a1[4];
  #pragma unroll
  for (int kg = 0; kg < 4; ++kg) {
    const size_t ab = ((size_t)kg * 65536 + e0 + lr) * 32 + lg * 8;
    a0[kg] = *(const short8v*)&att0[ab];
    a1[kg] = *(const short8v*)&att1[ab];
  }

  f32x4 acc[8];
  #pragma unroll
  for (int nt = 0; nt < 8; ++nt) acc[nt] = (f32x4){0.f, 0.f, 0.f, 0.f};
  #pragma unroll
  for (int nt = 0; nt < 8; ++nt) {
    const unsigned short* wrow = Wot + (size_t)(nt * 16 + lr) * 128;
    #pragma unroll
    for (int kg = 0; kg < 4; ++kg) {
      short8v bf = *(const short8v*)&wrow[kg * 32 + lg * 8];
      acc[nt] = MFMA16(a0[kg], bf, acc[nt]);
      acc[nt] = MFMA16(a1[kg], bf, acc[nt]);
    }
  }

  float bo_l[8], g_l[8], be_l[8];
  #pragma unroll
  for (int nt = 0; nt < 8; ++nt) {
    bo_l[nt] = bo[nt * 16 + lr];
    g_l[nt]  = gam[nt * 16 + lr];
    be_l[nt] = bet[nt * 16 + lr];
  }

  float s[4] = {}, s2[4] = {};
  #pragma unroll
  for (int nt = 0; nt < 8; ++nt)
    #pragma unroll
    for (int r = 0; r < 4; ++r) {
      const float res = ef[(size_t)(e0 + lg * 4 + r) * CF + nt * 16 + lr];
      const float v = acc[nt][r] + bo_l[nt] + res;
      acc[nt][r] = v;
      s[r] += v; s2[r] += v * v;
    }
  float mu[4], rstd[4], mk[4];
  #pragma unroll
  for (int r = 0; r < 4; ++r) {
    float a = s[r], b = s2[r];
    a += __shfl_xor(a, 1); b += __shfl_xor(b, 1);
    a += __shfl_xor(a, 2); b += __shfl_xor(b, 2);
    a += __shfl_xor(a, 4); b += __shfl_xor(b, 4);
    a += __shfl_xor(a, 8); b += __shfl_xor(b, 8);
    mu[r] = a * (1.f / 128.f);
    const float var = b * (1.f / 128.f) - mu[r] * mu[r];
    rstd[r] = rsqrtf(var + 1e-5f);
    mk[r] = maskg[e0 + lg * 4 + r];
  }
  #pragma unroll
  for (int nt = 0; nt < 8; ++nt)
    #pragma unroll
    for (int r = 0; r < 4; ++r) {
      const float yv = ((acc[nt][r] - mu[r]) * rstd[r] * g_l[nt] + be_l[nt]) * mk[r];
      outb[(size_t)(e0 + lg * 4 + r) * CF + nt * 16 + lr] = yv;
    }
}

// ---------------------------------------------------------------------------
extern "C" void kernel_launch(void* const* d_in, const int* in_sizes, int n_in,
                              void* d_out, int out_size, void* d_ws, size_t ws_size,
                              hipStream_t stream)
{
  (void)in_sizes; (void)n_in; (void)out_size; (void)ws_size;
  const float* ef   = (const float*)d_in[0];
  const float* mask = (const float*)d_in[1];
  const float* Wq   = (const float*)d_in[2];
  const float* Wk   = (const float*)d_in[3];
  const float* Wv   = (const float*)d_in[4];
  const float* Wo   = (const float*)d_in[5];
  const float* bo   = (const float*)d_in[6];
  const float* gam  = (const float*)d_in[7];
  const float* bet  = (const float*)d_in[8];
  float* out = (float*)d_out;
  const size_t BUF = (size_t)65536 * 128;       // 8M bf16 elems = 16MB
  unsigned short* Wt   = (unsigned short*)d_ws; // 4 x 16384 = 128KB
  unsigned short* Qn   = Wt + 4 * 16384;
  unsigned short* Kn   = Qn + BUF;
  unsigned short* Vn   = Kn + BUF;
  unsigned short* att0 = Vn + BUF;              // [4][65536][32] bf16 = 16MB
  unsigned short* att1 = att0 + BUF;            // total ~80.1MB

  k_cvt<<<dim3(4), dim3(256), 0, stream>>>(Wq, Wk, Wv, Wo, Wt);
  k_projM<<<dim3(1024), dim3(256), 0, stream>>>(ef, Wt, Qn, Kn, Vn);
  k_attn<<<dim3(256, 4, 2), dim3(512), 0, stream>>>(Qn, Kn, Vn, mask, att0, att1);
  k_finalM<<<dim3(1024), dim3(256), 0, stream>>>(out, ef, att0, att1,
                                                 Wt + 3 * 16384, bo, gam, bet, mask);
}

// Round 12
// 114.709 us; speedup vs baseline: 6.4369x; 1.0261x over previous
//
#include <hip/hip_runtime.h>
#include <hip/hip_bf16.h>
#include <math.h>

#define NQ 256      // D (grid side)
#define CF 128      // channels
#define RS 0.17677669529663687f   // 1/sqrt(32)
#define RSL2E 0.2550565392829014f // RS * log2(e): QK^T in log2 domain
#define NEGB -200.0f              // exp2(s-200) == 0.0f exactly for |s|<50

typedef __attribute__((ext_vector_type(8))) short short8v;   // 8 bf16 = 4 VGPR
typedef __attribute__((ext_vector_type(4))) float f32x4;

static __device__ __forceinline__ unsigned short f2bf(float x) {
  union { float f; unsigned u; } v; v.f = x;
  unsigned r = v.u + 0x7FFFu + ((v.u >> 16) & 1u);  // RNE
  return (unsigned short)(r >> 16);
}

// packed f32x2 -> bf16x2 (compiler emits v_cvt_pk_bf16_f32, hazards handled)
static __device__ __forceinline__ unsigned pack2(float a, float b) {
  __hip_bfloat162 h = __float22bfloat162_rn(make_float2(a, b));
  union { __hip_bfloat162 h; unsigned u; } c; c.h = h; return c.u;
}
static __device__ __forceinline__ unsigned long long pack4(float a, float b,
                                                           float c, float d) {
  return (unsigned long long)pack2(a, b) | ((unsigned long long)pack2(c, d) << 32);
}
static __device__ __forceinline__ short8v cvt8(float4 a, float4 b) {
  union { short8v s; unsigned u[4]; } r;
  r.u[0] = pack2(a.x, a.y); r.u[1] = pack2(a.z, a.w);
  r.u[2] = pack2(b.x, b.y); r.u[3] = pack2(b.z, b.w);
  return r.s;
}
#if __has_builtin(__builtin_amdgcn_exp2f)
#define EXP2F(x) __builtin_amdgcn_exp2f(x)
#else
#define EXP2F(x) exp2f(x)
#endif

#define MFMA16(a, b, c) __builtin_amdgcn_mfma_f32_16x16x32_bf16(a, b, c, 0, 0, 0)

// ---------------------------------------------------------------------------
// K0: weight prep. Wt[y][n][k] = bf16(W_y[k][n]), y in {q,k,v,o}. RS*log2e
// folded into Wq. grid 4 x 256.
// ---------------------------------------------------------------------------
extern "C" __global__ __launch_bounds__(256) void k_cvt(
    const float* __restrict__ Wq, const float* __restrict__ Wk,
    const float* __restrict__ Wv, const float* __restrict__ Wo,
    unsigned short* __restrict__ Wt)
{
  const int y = blockIdx.x;
  const float* W = (y == 0) ? Wq : (y == 1) ? Wk : (y == 2) ? Wv : Wo;
  unsigned short* dst = Wt + (size_t)y * 16384;
  const float sc = (y == 0) ? RSL2E : 1.0f;
  const int t = threadIdx.x;
  #pragma unroll
  for (int i = 0; i < 16; ++i) {
    const int flat = (t + 256 * i) * 4;
    const int k = flat >> 7, n = flat & 127;
    float4 v = *(const float4*)&W[flat];
    dst[(n + 0) * 128 + k] = f2bf(v.x * sc);
    dst[(n + 1) * 128 + k] = f2bf(v.y * sc);
    dst[(n + 2) * 128 + k] = f2bf(v.z * sc);
    dst[(n + 3) * 128 + k] = f2bf(v.w * sc);
  }
}

// ---------------------------------------------------------------------------
// K1: MFMA projection -> edge-major bf16 Q/K/V. grid 1024, block 256
// (4 waves). B-frags register-resident (launch_bounds(256,2) for VGPR room).
// D-frags stashed in LDS, re-read b128 -> full 256B-per-row coalesced stores
// (fixes r9-r11's 8B-scatter write fragmentation at 1.1 TB/s).
// ---------------------------------------------------------------------------
extern "C" __global__ __launch_bounds__(256, 2) void k_projM(
    const float* __restrict__ ef, const unsigned short* __restrict__ Wt,
    unsigned short* __restrict__ Qn, unsigned short* __restrict__ Kn,
    unsigned short* __restrict__ Vn)
{
  __shared__ unsigned short ol[3][16][136];   // [y][edge][ch] pad 8 -> 13KB
  const int t = threadIdx.x, w = t >> 6, l = t & 63;
  const int lr = l & 15, lg = l >> 4;
  const int n0 = w * 32;

  short8v bfrag[3][2][4];
  #pragma unroll
  for (int y = 0; y < 3; ++y)
    #pragma unroll
    for (int nt = 0; nt < 2; ++nt) {
      const unsigned short* wrow = Wt + (size_t)y * 16384
                                   + (size_t)(n0 + nt * 16 + lr) * 128;
      #pragma unroll
      for (int kg = 0; kg < 4; ++kg)
        bfrag[y][nt][kg] = *(const short8v*)&wrow[kg * 32 + lg * 8];
    }

  const int row = t >> 4, cb = (t & 15) * 8;
  #pragma unroll
  for (int si = 0; si < 4; ++si) {
    const int es = (blockIdx.x * 4 + si) * 16;
    __syncthreads();   // prev strip's ol reads complete
    short8v af[4];
    const float* arow = ef + (size_t)(es + lr) * CF;
    #pragma unroll
    for (int kg = 0; kg < 4; ++kg) {
      float4 a = *(const float4*)&arow[kg * 32 + lg * 8];
      float4 b = *(const float4*)&arow[kg * 32 + lg * 8 + 4];
      af[kg] = cvt8(a, b);
    }
    #pragma unroll
    for (int y = 0; y < 3; ++y)
      #pragma unroll
      for (int nt = 0; nt < 2; ++nt) {
        f32x4 acc = {0.f, 0.f, 0.f, 0.f};
        #pragma unroll
        for (int kg = 0; kg < 4; ++kg)
          acc = MFMA16(bfrag[y][nt][kg], af[kg], acc);
        // D: col(lr)=edge, row(lg*4+r)=channel n0+nt*16+lg*4+r
        *(unsigned long long*)&ol[y][lr][n0 + nt * 16 + lg * 4] =
            pack4(acc[0], acc[1], acc[2], acc[3]);
      }
    __syncthreads();   // stash visible to whole block
    #pragma unroll
    for (int y = 0; y < 3; ++y) {
      unsigned short* Nb = (y == 0) ? Qn : (y == 1) ? Kn : Vn;
      short8v v = *(const short8v*)&ol[y][row][cb];
      *(short8v*)&Nb[(size_t)(es + row) * CF + cb] = v;   // 256B per row
    }
  }
}

// ---------------------------------------------------------------------------
// K2: MFMA attention, operand-swapped, base-2 softmax, mask folded into the
// MFMA C-operand (bias 0 / -200 in log2 domain -> exp2 yields exact 0).
// Block = (slice cr, head h, mode z), 8 waves x 32 q. Output bf16 head-major
// att[h][edge][32], 0.5/rowsum folded.
// ---------------------------------------------------------------------------
extern "C" __global__ __launch_bounds__(512, 2) void k_attn(
    const unsigned short* __restrict__ Qn, const unsigned short* __restrict__ Kn,
    const unsigned short* __restrict__ Vn, const float* __restrict__ maskg,
    unsigned short* __restrict__ att0, unsigned short* __restrict__ att1)
{
  __shared__ unsigned short Kl[256][40];   // [k][d] pad 8
  __shared__ unsigned short Vl[32][264];   // [d][k] pad 8 (264 u16 = 132 banks)
  __shared__ float biasl[256];             // 0 or -200 (log2 domain)
  __shared__ unsigned short Pb[8][32][40]; // per-wave P chunk [q][k] pad 8
  const int cr = blockIdx.x, h = blockIdx.y, mode = blockIdx.z;
  const int t = threadIdx.x, w = t >> 6, l = t & 63;
  const int lr = l & 15, lg = l >> 4;

  {  // K staging: b128 row-major
    const int k = t >> 1, dh = t & 1;
    const size_t eb = (mode ? ((size_t)cr * NQ + k) : ((size_t)k * NQ + cr)) * CF
                      + h * 32 + dh * 16;
    short8v ka = *(const short8v*)(Kn + eb);
    short8v kb = *(const short8v*)(Kn + eb + 8);
    *(short8v*)&Kl[k][dh * 16] = ka;
    *(short8v*)&Kl[k][dh * 16 + 8] = kb;
  }
  {  // V staging: d-major transpose via packed u32 writes (k-pairs)
    const int j = t & 127, db = t >> 7;    // k = 2j,2j+1; d-base = db*8
    const size_t e0 = (mode ? ((size_t)cr * NQ + 2 * j)
                            : ((size_t)(2 * j) * NQ + cr)) * CF + h * 32 + db * 8;
    const size_t e1 = (mode ? ((size_t)cr * NQ + 2 * j + 1)
                            : ((size_t)(2 * j + 1) * NQ + cr)) * CF + h * 32 + db * 8;
    short8v va = *(const short8v*)(Vn + e0);
    short8v vb = *(const short8v*)(Vn + e1);
    unsigned* Vl32 = (unsigned*)&Vl[0][0];
    #pragma unroll
    for (int i = 0; i < 8; ++i)
      Vl32[(db * 8 + i) * 132 + j] =
          (unsigned)(unsigned short)va[i] |
          ((unsigned)(unsigned short)vb[i] << 16);
  }
  if (t < 256) {
    const float mv = mode ? maskg[(size_t)cr * NQ + t] : maskg[(size_t)t * NQ + cr];
    biasl[t] = (mv == 0.f) ? NEGB : 0.f;
  }
  const int q0 = w * 32;
  short8v qf[2];
  #pragma unroll
  for (int qt = 0; qt < 2; ++qt) {
    const int q = q0 + qt * 16 + lr;
    const size_t eq = (mode ? ((size_t)cr * NQ + q) : ((size_t)q * NQ + cr)) * CF
                      + h * 32 + lg * 8;
    qf[qt] = *(const short8v*)(Qn + eq);
  }
  __syncthreads();

  f32x4 outv[2][2];   // [qt][dt]: D col=q(lr), row=d(lg*4+r)
  #pragma unroll
  for (int qt = 0; qt < 2; ++qt)
    #pragma unroll
    for (int dt = 0; dt < 2; ++dt) outv[qt][dt] = (f32x4){0.f, 0.f, 0.f, 0.f};
  float psum[2] = {0.f, 0.f};

  #pragma unroll
  for (int kc = 0; kc < 8; ++kc) {
    #pragma unroll
    for (int kth = 0; kth < 2; ++kth) {
      const int kt = kc * 2 + kth;
      short8v kf = *(const short8v*)&Kl[kt * 16 + lr][lg * 8];
      f32x4 z = *(const f32x4*)&biasl[kt * 16 + lg * 4];  // bias in C
      #pragma unroll
      for (int qt = 0; qt < 2; ++qt) {
        f32x4 s = MFMA16(kf, qf[qt], z);   // swapped: col=q, row=k (log2 domain)
        const float p0 = EXP2F(s[0]);
        const float p1 = EXP2F(s[1]);
        const float p2 = EXP2F(s[2]);
        const float p3 = EXP2F(s[3]);
        psum[qt] += (p0 + p1) + (p2 + p3);
        *(unsigned long long*)&Pb[w][qt * 16 + lr][kth * 16 + lg * 4] =
            pack4(p0, p1, p2, p3);
      }
    }
    asm volatile("s_waitcnt lgkmcnt(0)" ::: "memory");
    short8v vf[2];
    #pragma unroll
    for (int dt = 0; dt < 2; ++dt)
      vf[dt] = *(const short8v*)&Vl[dt * 16 + lr][kc * 32 + lg * 8];
    #pragma unroll
    for (int qt = 0; qt < 2; ++qt) {
      short8v pf = *(const short8v*)&Pb[w][qt * 16 + lr][lg * 8];
      #pragma unroll
      for (int dt = 0; dt < 2; ++dt)
        outv[qt][dt] = MFMA16(vf[dt], pf, outv[qt][dt]);  // swapped: col=q, row=d
    }
  }

  // rowsum: lane-scalar, reduce across the 4 lg-groups (lane bits 4,5)
  float inv[2];
  #pragma unroll
  for (int qt = 0; qt < 2; ++qt) {
    float ssum = psum[qt];
    ssum += __shfl_xor(ssum, 16);
    ssum += __shfl_xor(ssum, 32);
    inv[qt] = 0.5f / ssum;
  }
  #pragma unroll
  for (int qt = 0; qt < 2; ++qt)
    #pragma unroll
    for (int dt = 0; dt < 2; ++dt)
      *(unsigned long long*)&Pb[w][qt * 16 + lr][dt * 16 + lg * 4] =
          pack4(outv[qt][dt][0] * inv[qt], outv[qt][dt][1] * inv[qt],
                outv[qt][dt][2] * inv[qt], outv[qt][dt][3] * inv[qt]);
  asm volatile("s_waitcnt lgkmcnt(0)" ::: "memory");
  short8v o0 = *(const short8v*)&Pb[w][l >> 1][(l & 1) * 16];
  short8v o1 = *(const short8v*)&Pb[w][l >> 1][(l & 1) * 16 + 8];
  asm volatile("s_waitcnt lgkmcnt(0)" ::: "memory");
  unsigned short* dst = mode ? att1 : att0;
  const int q = q0 + (l >> 1);
  const size_t edge = mode ? ((size_t)cr * NQ + q) : ((size_t)q * NQ + cr);
  const size_t ob = ((size_t)h * 65536 + edge) * 32 + (l & 1) * 16;
  *(short8v*)&dst[ob] = o0;
  *(short8v*)&dst[ob + 8] = o1;
}

// ---------------------------------------------------------------------------
// K3: MFMA out-proj + bias + residual + LayerNorm + mask -> d_out (f32).
// grid 1024, block 256 (4 waves). A = att0,att1 (bf16 head-major), summed
// via two MFMA chains. LN reduced in D-frag registers via shfl_xor.
// ---------------------------------------------------------------------------
extern "C" __global__ __launch_bounds__(256) void k_finalM(
    float* __restrict__ outb, const float* __restrict__ ef,
    const unsigned short* __restrict__ att0, const unsigned short* __restrict__ att1,
    const unsigned short* __restrict__ Wot, const float* __restrict__ bo,
    const float* __restrict__ gam, const float* __restrict__ bet,
    const float* __restrict__ maskg)
{
  const int t = threadIdx.x, w = t >> 6, l = t & 63;
  const int lr = l & 15, lg = l >> 4;
  const int e0 = blockIdx.x * 64 + w * 16;   // wave strip base

  short8v a0[4], a1[4];
  #pragma unroll
  for (int kg = 0; kg < 4; ++kg) {
    const size_t ab = ((size_t)kg * 65536 + e0 + lr) * 32 + lg * 8;
    a0[kg] = *(const short8v*)&att0[ab];
    a1[kg] = *(const short8v*)&att1[ab];
  }

  f32x4 acc[8];
  #pragma unroll
  for (int nt = 0; nt < 8; ++nt) acc[nt] = (f32x4){0.f, 0.f, 0.f, 0.f};
  #pragma unroll
  for (int nt = 0; nt < 8; ++nt) {
    const unsigned short* wrow = Wot + (size_t)(nt * 16 + lr) * 128;
    #pragma unroll
    for (int kg = 0; kg < 4; ++kg) {
      short8v bf = *(const short8v*)&wrow[kg * 32 + lg * 8];
      acc[nt] = MFMA16(a0[kg], bf, acc[nt]);
      acc[nt] = MFMA16(a1[kg], bf, acc[nt]);
    }
  }

  float bo_l[8], g_l[8], be_l[8];
  #pragma unroll
  for (int nt = 0; nt < 8; ++nt) {
    bo_l[nt] = bo[nt * 16 + lr];
    g_l[nt]  = gam[nt * 16 + lr];
    be_l[nt] = bet[nt * 16 + lr];
  }

  float s[4] = {}, s2[4] = {};
  #pragma unroll
  for (int nt = 0; nt < 8; ++nt)
    #pragma unroll
    for (int r = 0; r < 4; ++r) {
      const float res = ef[(size_t)(e0 + lg * 4 + r) * CF + nt * 16 + lr];
      const float v = acc[nt][r] + bo_l[nt] + res;
      acc[nt][r] = v;
      s[r] += v; s2[r] += v * v;
    }
  float mu[4], rstd[4], mk[4];
  #pragma unroll
  for (int r = 0; r < 4; ++r) {
    float a = s[r], b = s2[r];
    a += __shfl_xor(a, 1); b += __shfl_xor(b, 1);
    a += __shfl_xor(a, 2); b += __shfl_xor(b, 2);
    a += __shfl_xor(a, 4); b += __shfl_xor(b, 4);
    a += __shfl_xor(a, 8); b += __shfl_xor(b, 8);
    mu[r] = a * (1.f / 128.f);
    const float var = b * (1.f / 128.f) - mu[r] * mu[r];
    rstd[r] = rsqrtf(var + 1e-5f);
    mk[r] = maskg[e0 + lg * 4 + r];
  }
  #pragma unroll
  for (int nt = 0; nt < 8; ++nt)
    #pragma unroll
    for (int r = 0; r < 4; ++r) {
      const float yv = ((acc[nt][r] - mu[r]) * rstd[r] * g_l[nt] + be_l[nt]) * mk[r];
      outb[(size_t)(e0 + lg * 4 + r) * CF + nt * 16 + lr] = yv;
    }
}

// ---------------------------------------------------------------------------
extern "C" void kernel_launch(void* const* d_in, const int* in_sizes, int n_in,
                              void* d_out, int out_size, void* d_ws, size_t ws_size,
                              hipStream_t stream)
{
  (void)in_sizes; (void)n_in; (void)out_size; (void)ws_size;
  const float* ef   = (const float*)d_in[0];
  const float* mask = (const float*)d_in[1];
  const float* Wq   = (const float*)d_in[2];
  const float* Wk   = (const float*)d_in[3];
  const float* Wv   = (const float*)d_in[4];
  const float* Wo   = (const float*)d_in[5];
  const float* bo   = (const float*)d_in[6];
  const float* gam  = (const float*)d_in[7];
  const float* bet  = (const float*)d_in[8];
  float* out = (float*)d_out;
  const size_t BUF = (size_t)65536 * 128;       // 8M bf16 elems = 16MB
  unsigned short* Wt   = (unsigned short*)d_ws; // 4 x 16384 = 128KB
  unsigned short* Qn   = Wt + 4 * 16384;
  unsigned short* Kn   = Qn + BUF;
  unsigned short* Vn   = Kn + BUF;
  unsigned short* att0 = Vn + BUF;              // [4][65536][32] bf16 = 16MB
  unsigned short* att1 = att0 + BUF;            // total ~80.1MB

  k_cvt<<<dim3(4), dim3(256), 0, stream>>>(Wq, Wk, Wv, Wo, Wt);
  k_projM<<<dim3(1024), dim3(256), 0, stream>>>(ef, Wt, Qn, Kn, Vn);
  k_attn<<<dim3(256, 4, 2), dim3(512), 0, stream>>>(Qn, Kn, Vn, mask, att0, att1);
  k_finalM<<<dim3(1024), dim3(256), 0, stream>>>(out, ef, att0, att1,
                                                 Wt + 3 * 16384, bo, gam, bet, mask);
}